// Round 9
// baseline (350.017 us; speedup 1.0000x reference)
//
#include <hip/hip_runtime.h>
#include <math.h>

#define BATCH 8
#define SEQ   2048      // LQ == LK
#define DIM   1024      // DQ == DK == DV
#define TOPK  64
#define NEGMASK -1e30f
#define CAND_THRESH 16.0f   // drop alpha <= e^-16: g <= 1.1e-7, invisible at 2e-3
#define CAP 28              // candidate slots per [row][64-col group]

typedef _Float16 f16;
typedef _Float16 f16x8 __attribute__((ext_vector_type(8)));
typedef float f32x4 __attribute__((ext_vector_type(4)));

// async global->LDS, 16B per lane; LDS dest is wave-uniform base + lane*16.
__device__ __forceinline__ void async_load16(const void* g, void* l) {
  __builtin_amdgcn_global_load_lds(
      (const __attribute__((address_space(1))) void*)g,
      (__attribute__((address_space(3))) void*)l, 16, 0, 0);
}

// ---------------- prep1: cvt(Q), cvt(W), pack_mask, colsum_partial ----------------
// Independent ops fused into one launch; dispatch by block range.
// mask-bit layout: word (grp*4 + j), bit l <-> column grp*256 + 4*l + j.
__global__ __launch_bounds__(256) void prep1_kernel(
    const float* __restrict__ queries, const float* __restrict__ W,
    const int4* __restrict__ mask4, const float* __restrict__ values,
    f16* __restrict__ q16, f16* __restrict__ w16,
    unsigned long long* __restrict__ mb, float* __restrict__ partial) {
  const int blk = blockIdx.x;
  if (blk < 16384) {                       // cvt queries (16M elems)
    int i = (blk * 256 + threadIdx.x) * 4;
    float4 v = *(const float4*)(queries + i);
    union { f16 h[4]; uint2 u; } pk;
    pk.h[0] = (f16)v.x; pk.h[1] = (f16)v.y; pk.h[2] = (f16)v.z; pk.h[3] = (f16)v.w;
    *(uint2*)(q16 + i) = pk.u;
  } else if (blk < 17408) {                // cvt W (1M elems)
    int i = ((blk - 16384) * 256 + threadIdx.x) * 4;
    float4 v = *(const float4*)(W + i);
    union { f16 h[4]; uint2 u; } pk;
    pk.h[0] = (f16)v.x; pk.h[1] = (f16)v.y; pk.h[2] = (f16)v.z; pk.h[3] = (f16)v.w;
    *(uint2*)(w16 + i) = pk.u;
  } else if (blk < 19456) {                // pack_mask (2048 virtual blocks)
    const int bid = blk - 17408;
    const int wave = threadIdx.x >> 6, lane = threadIdx.x & 63;
    const size_t nGrp = (size_t)16384 * 8;
    for (size_t g = (size_t)bid * 8 + wave * 2; g < nGrp; g += 2048 * 8) {
      int4 v0 = mask4[g * 64 + lane];
      int4 v1 = mask4[(g + 1) * 64 + lane];
      unsigned long long a0 = __ballot(v0.x != 0);
      unsigned long long a1 = __ballot(v0.y != 0);
      unsigned long long a2 = __ballot(v0.z != 0);
      unsigned long long a3 = __ballot(v0.w != 0);
      unsigned long long b0 = __ballot(v1.x != 0);
      unsigned long long b1 = __ballot(v1.y != 0);
      unsigned long long b2 = __ballot(v1.z != 0);
      unsigned long long b3 = __ballot(v1.w != 0);
      if (lane == 0) {
        mb[g * 4 + 0] = a0; mb[g * 4 + 1] = a1;
        mb[g * 4 + 2] = a2; mb[g * 4 + 3] = a3;
        mb[g * 4 + 4] = b0; mb[g * 4 + 5] = b1;
        mb[g * 4 + 6] = b2; mb[g * 4 + 7] = b3;
      }
    }
  } else {                                 // colsum_partial (256 virtual blocks)
    const int bid = blk - 19456;
    int tc = bid >> 5;
    int b  = (bid >> 2) & 7;
    int dg = bid & 3;
    int d  = dg * 256 + threadIdx.x;
    const float* vp = values + ((size_t)b * SEQ + (size_t)tc * 256) * DIM + d;
    float s = 0.f;
    #pragma unroll 8
    for (int t = 0; t < 256; ++t) s += vp[(size_t)t * DIM];
    partial[((size_t)tc * BATCH + b) * DIM + d] = s;
  }
}

// ---------------- prep2: cvt(keys), colsum_reduce ----------------
__global__ __launch_bounds__(256) void prep2_kernel(
    const float* __restrict__ keys, const float* __restrict__ partial,
    f16* __restrict__ k16, float* __restrict__ colsum) {
  const int blk = blockIdx.x;
  if (blk < 16384) {                       // cvt keys (16M elems)
    int i = (blk * 256 + threadIdx.x) * 4;
    float4 v = *(const float4*)(keys + i);
    union { f16 h[4]; uint2 u; } pk;
    pk.h[0] = (f16)v.x; pk.h[1] = (f16)v.y; pk.h[2] = (f16)v.z; pk.h[3] = (f16)v.w;
    *(uint2*)(k16 + i) = pk.u;
  } else {                                 // colsum_reduce (32 virtual blocks)
    int idx = (blk - 16384) * 256 + threadIdx.x;   // 8192
    float s = 0.f;
    #pragma unroll
    for (int tc = 0; tc < 8; ++tc) s += partial[(size_t)tc * 8192 + idx];
    colsum[idx] = s;
  }
}

// ---------------- MFMA bt-GEMM core (fp16, 2-phase dbuf, 128x64 tile) ----------------
// 256 thr = 4 waves stacked in M (32 rows each), all sharing the 64-col B panel.
// Per-wave: acc[2][4] (32 AGPR), af[2]+bf[4] (24 VGPR) -> ~90 combined regs
// -> 4-5 waves/SIMD; LDS 24 KB (2 x [A 8K | B 4K]) -> 6 blocks -> high residency
// hides the per-K-step drain (r8 mechanism, confirmed: occ 21->29% gave 131->118).
// Staging: 2 A-loads + 1 B-load per wave per K-step via global_load_lds.
// Slot XOR-swizzle (rule #21): linear LDS dest, inverse-swizzled global src,
// swizzled ds_read_b128 (SQ_LDS_BANK_CONFLICT==0 verified r5-r8).

#define STAGEK(KOFF, BUF)                                                   \
  async_load16(srcA0 + (KOFF), sm + (BUF) * 12288 + wave * 2048);           \
  async_load16(srcA1 + (KOFF), sm + (BUF) * 12288 + wave * 2048 + 1024);    \
  async_load16(srcB0 + (KOFF), sm + (BUF) * 12288 + 8192 + wave * 1024);

#define GEMM_PROLOGUE(APTR, BPTR)                                           \
  const int tid = threadIdx.x;                                              \
  const int wave = tid >> 6, lane = tid & 63;                               \
  const int lcq = lane >> 4, l15 = lane & 15;                               \
  const int r0 = wave * 32 + (lane >> 2);                                   \
  const int c16 = (lane & 3) ^ ((r0 >> 1) & 3);                            \
  const int r0b = wave * 16 + (lane >> 2);                                  \
  const int c16b = (lane & 3) ^ ((r0b >> 1) & 3);                          \
  const f16* srcA0 = (APTR) + (size_t)(m0 + r0) * DIM + c16 * 8;           \
  const f16* srcA1 = (APTR) + (size_t)(m0 + r0 + 16) * DIM + c16 * 8;      \
  const f16* srcB0 = (BPTR) + (size_t)(n0 + r0b) * DIM + c16b * 8;         \
  int offA[2], offB[4];                                                     \
  _Pragma("unroll")                                                         \
  for (int fm = 0; fm < 2; ++fm) {                                          \
    int r = wave * 32 + fm * 16 + l15;                                      \
    offA[fm] = r * 64 + (lcq ^ ((r >> 1) & 3)) * 16;                        \
  }                                                                         \
  _Pragma("unroll")                                                         \
  for (int fn = 0; fn < 4; ++fn) {                                          \
    int rn = fn * 16 + l15;                                                 \
    offB[fn] = 8192 + rn * 64 + (lcq ^ ((rn >> 1) & 3)) * 16;               \
  }                                                                         \
  f32x4 acc[2][4];                                                          \
  _Pragma("unroll")                                                         \
  for (int i = 0; i < 2; ++i)                                               \
    _Pragma("unroll")                                                       \
    for (int j = 0; j < 4; ++j)                                             \
      acc[i][j] = (f32x4){0.f, 0.f, 0.f, 0.f};                              \
  STAGEK(0, 0)                                                              \
  __syncthreads();                                                          \
  int cur = 0;                                                              \
  for (int k0 = 0; k0 < DIM; k0 += 32) {                                    \
    const int nxt = cur ^ 1;                                                \
    if (k0 + 32 < DIM) { STAGEK(k0 + 32, nxt) }                             \
    f16x8 af[2], bf[4];                                                     \
    _Pragma("unroll")                                                       \
    for (int fm = 0; fm < 2; ++fm)                                          \
      af[fm] = *(const f16x8*)(sm + cur * 12288 + offA[fm]);                \
    _Pragma("unroll")                                                       \
    for (int fn = 0; fn < 4; ++fn)                                          \
      bf[fn] = *(const f16x8*)(sm + cur * 12288 + offB[fn]);                \
    _Pragma("unroll")                                                       \
    for (int fm = 0; fm < 2; ++fm)                                          \
      _Pragma("unroll")                                                     \
      for (int fn = 0; fn < 4; ++fn)                                        \
        acc[fm][fn] = __builtin_amdgcn_mfma_f32_16x16x32_f16(               \
            af[fm], bf[fn], acc[fm][fn], 0, 0, 0);                          \
    __syncthreads();                                                        \
    cur = nxt;                                                              \
  }

__global__ __launch_bounds__(256, 4) void gemm_qproj(
    const f16* __restrict__ A, const f16* __restrict__ Bw,
    f16* __restrict__ C) {
  __shared__ __align__(128) char sm[24576];
  // XCD-swizzled: 2048 blocks = 128 m-tiles x 16 n-tiles
  const int swz = (blockIdx.x & 7) * 256 + (blockIdx.x >> 3);
  const int m0 = (swz >> 4) * 128;
  const int n0 = (swz & 15) * 64;
  GEMM_PROLOGUE(A, Bw)
  // C/D layout (verified r2+): col = lane&15, row = (lane>>4)*4 + reg
  #pragma unroll
  for (int fm = 0; fm < 2; ++fm)
    #pragma unroll
    for (int reg = 0; reg < 4; ++reg) {
      const int cr = m0 + wave * 32 + fm * 16 + lcq * 4 + reg;
      #pragma unroll
      for (int fn = 0; fn < 4; ++fn)
        C[(size_t)cr * DIM + n0 + fn * 16 + l15] = (f16)acc[fm][fn][reg];
    }
}

// scores GEMM + fused mask + per-row 64-col group max + candidate emission.
// Emits per [row][64-col group] the set {s > groupmax - 16} (superset of the
// global {s > mv-16} within those cols; groupmax <= mv). Rows live entirely
// in one wave -> no cross-wave combine. cand/counts layout unchanged (32
// groups of 64 cols per row) -> topk kernel identical to r5-r8.
__global__ __launch_bounds__(256, 4) void gemm_scores(
    const f16* __restrict__ QP, const f16* __restrict__ K16,
    const unsigned long long* __restrict__ maskbits,  // [16384][32]
    float2* __restrict__ cand,                        // [16384][32][CAP]
    int* __restrict__ counts) {                       // [16384][32]
  __shared__ __align__(128) char sm[24576];
  // XCD-swizzled: 4096 blocks = 128 m-tiles x 32 n-tiles; XCD x -> batch x
  const int swz = (blockIdx.x & 7) * 512 + (blockIdx.x >> 3);
  const int m0 = (swz >> 5) * 128;     // global flat q-row tile
  const int n0 = (swz & 31) * 64;      // t col within batch
  const int b  = m0 >> 11;
  const f16* Bk = K16 + (size_t)b * SEQ * DIM;
  GEMM_PROLOGUE(QP, Bk)

  // mask bits for cols n0 + fn*16 + l15: word grp*4 + (l15&3),
  // bit basebit + fn*4 + (l15>>2)   (wn==0 case of the r5-verified algebra)
  const int grp = n0 >> 8;
  const int basebit = (n0 & 255) >> 2;
  const int pairb = n0 >> 6;           // 64-col group index 0..31
  #pragma unroll
  for (int fm = 0; fm < 2; ++fm)
    #pragma unroll
    for (int reg = 0; reg < 4; ++reg) {
      const int rloc = wave * 32 + fm * 16 + lcq * 4 + reg;
      const size_t grow = (size_t)m0 + rloc;
      const unsigned long long mw = maskbits[grow * 32 + grp * 4 + (l15 & 3)];
      #pragma unroll
      for (int fn = 0; fn < 4; ++fn)
        if (!((mw >> (basebit + fn * 4 + (l15 >> 2))) & 1ull))
          acc[fm][fn][reg] = NEGMASK;
      // row max over this block's 64 cols (in-reg + 16-lane reduce)
      float m4 = fmaxf(fmaxf(acc[fm][0][reg], acc[fm][1][reg]),
                       fmaxf(acc[fm][2][reg], acc[fm][3][reg]));
      #pragma unroll
      for (int off = 8; off >= 1; off >>= 1) m4 = fmaxf(m4, __shfl_xor(m4, off));
      const float thresh = fmaxf(m4 - CAND_THRESH, -1e29f);
      // ballot-compact candidates (deterministic: slot = running popcount)
      float2* slot = cand + (grow * 32 + pairb) * CAP;
      int cnt = 0;
      #pragma unroll
      for (int fn = 0; fn < 4; ++fn) {
        const float s = acc[fm][fn][reg];
        const bool c = s > thresh;
        const unsigned long long bal = __ballot(c);
        const int seg = (int)((bal >> (lcq * 16)) & 0xFFFFull);
        const int pos = cnt + __popc(seg & ((1 << l15) - 1));
        if (c && pos < CAP) {
          float2 e; e.x = s; e.y = __int_as_float(n0 + fn * 16 + l15);
          slot[pos] = e;
        }
        cnt += __popc(seg);
      }
      if (l15 == 0) counts[grow * 32 + pairb] = cnt < CAP ? cnt : CAP;
    }
}

// ---------------- topk from candidate lists (unchanged from r5-r8) ----------------
__global__ __launch_bounds__(512) void topk_kernel(
    const float2* __restrict__ cand,       // [16384][32][CAP]
    const int*    __restrict__ counts,     // [16384][32]
    const float*  __restrict__ values,     // [8][2048][1024]
    const float*  __restrict__ colsum,     // [8][1024]
    float* __restrict__ out)               // [16384][1024]
{
  __shared__ float ssc[8][128];
  __shared__ int   sidx[8][128];
  const int wave = threadIdx.x >> 6;
  const int lane = threadIdx.x & 63;
  const int grow = blockIdx.x * 8 + wave;      // global flat q-row
  const int b    = grow >> 11;
  float* msc = ssc[wave];
  int*   mix = sidx[wave];

  int cnt_p = 0;
  if (lane < 32) cnt_p = counts[(size_t)grow * 32 + lane];
  const float2* myslots = cand + ((size_t)grow * 32 + lane) * CAP;

  // pass 1: global row max over candidates
  float mv = -3e38f;
  for (int k = 0; k < cnt_p; ++k) mv = fmaxf(mv, myslots[k].x);
  #pragma unroll
  for (int off = 32; off > 0; off >>= 1) mv = fmaxf(mv, __shfl_xor(mv, off));
  const bool dead = (mv <= -1e29f);   // fully-masked row -> uniform softmax

  float total_g = 0.f;
  f32x4 oacc[4];
  #pragma unroll
  for (int j = 0; j < 4; ++j) oacc[j] = (f32x4){0.f, 0.f, 0.f, 0.f};
  const float* vbase = values + (size_t)b * SEQ * DIM;

  if (!dead) {
    const float thresh = mv - CAND_THRESH;
    // pass 2: filter count + Z partial
    int f = 0; float zp = 0.f;
    for (int k = 0; k < cnt_p; ++k) {
      float s = myslots[k].x;
      if (s > thresh) { ++f; zp += __expf(s - mv); }
    }
    // prefix over 64 lanes for deterministic compaction order
    int incl = f;
    #pragma unroll
    for (int off = 1; off < 64; off <<= 1) {
      int t = __shfl_up(incl, off);
      if (lane >= off) incl += t;
    }
    const int base = incl - f;
    const int F = __shfl(incl, 63);
    #pragma unroll
    for (int off = 32; off > 0; off >>= 1) zp += __shfl_xor(zp, off);
    const float Z = zp;
    // compact filtered candidates to LDS (order: (group, slot))
    int w = 0;
    for (int k = 0; k < cnt_p; ++k) {
      float2 cv = myslots[k];
      if (cv.x > thresh) {
        int p = base + w;
        if (p < 128) { msc[p] = cv.x; mix[p] = __float_as_int(cv.y); }
        ++w;
      }
    }
    asm volatile("s_waitcnt lgkmcnt(0)" ::: "memory");

    if (F <= TOPK) {
      // common path: filtered set == significant top-k members
      for (int c = 0; c < F; ++c) {
        float g = expm1f(__expf(msc[c] - mv) / Z);
        total_g += g;
        const float* vrow = vbase + (size_t)mix[c] * DIM;
        #pragma unroll
        for (int j = 0; j < 4; ++j) {
          f32x4 v = *(const f32x4*)(vrow + j * 256 + lane * 4);
          #pragma unroll
          for (int e = 0; e < 4; ++e) oacc[j][e] = fmaf(g, v[e], oacc[j][e]);
        }
      }
    } else {
      // rare path: exact top-64 by (score desc, idx asc) from the list
      const int nlist = F < 128 ? F : 128;
      for (int itk = 0; itk < TOPK; ++itk) {
        float bv = -3e38f; int bi = 1 << 30; int bsl = -1;
        #pragma unroll
        for (int h = 0; h < 2; ++h) {
          int sl = lane + h * 64;
          if (sl < nlist) {
            float v = msc[sl]; int id = mix[sl];
            if (v > bv || (v == bv && id < bi)) { bv = v; bi = id; bsl = sl; }
          }
        }
        #pragma unroll
        for (int off = 32; off > 0; off >>= 1) {
          float ov = __shfl_xor(bv, off);
          int   oi = __shfl_xor(bi, off);
          int   os = __shfl_xor(bsl, off);
          if (ov > bv || (ov == bv && oi < bi)) { bv = ov; bi = oi; bsl = os; }
        }
        if (bv <= -1e29f) break;
        float g = expm1f(__expf(bv - mv) / Z);
        total_g += g;
        const float* vrow = vbase + (size_t)bi * DIM;
        #pragma unroll
        for (int j = 0; j < 4; ++j) {
          f32x4 v = *(const f32x4*)(vrow + j * 256 + lane * 4);
          #pragma unroll
          for (int e = 0; e < 4; ++e) oacc[j][e] = fmaf(g, v[e], oacc[j][e]);
        }
        if (lane == 0) msc[bsl] = -3e38f;
        asm volatile("s_waitcnt lgkmcnt(0)" ::: "memory");
      }
    }
  }

  // out = (colsum + sum g*v) / (2048 + sum g)
  const float inv = 1.0f / (2048.0f + total_g);
  const float* cs = colsum + (size_t)b * DIM;
  float* orow = out + (size_t)grow * DIM;
  #pragma unroll
  for (int j = 0; j < 4; ++j) {
    f32x4 c = *(const f32x4*)(cs + j * 256 + lane * 4);
    f32x4 o;
    #pragma unroll
    for (int e = 0; e < 4; ++e) o[e] = (c[e] + oacc[j][e]) * inv;
    *(f32x4*)(orow + j * 256 + lane * 4) = o;
  }
}

extern "C" void kernel_launch(void* const* d_in, const int* in_sizes, int n_in,
                              void* d_out, int out_size, void* d_ws, size_t ws_size,
                              hipStream_t stream) {
  const float* queries = (const float*)d_in[0];
  const float* keys    = (const float*)d_in[1];
  const float* values  = (const float*)d_in[2];
  const int*   mask    = (const int*)d_in[3];
  const float* W       = (const float*)d_in[4];
  float* out = (float*)d_out;

  // ws layout (bytes), total ~192.3 MB (same proven footprint):
  //   [0, 112M)    cand float2[16384][32][28]
  //       q16 aliases [0, 32M)   (dead before gemm_scores)
  //       w16 aliases [32M, 34M) (dead before gemm_scores)
  //   [112M, 114M) counts int[16384][32]
  //   [114M, 118M) maskbits u64[16384][32]
  //   [128M, 160M) qp16 f16 [16384][1024]
  //   [160M, 192M) k16  f16 [8][2048][1024]
  //   [192M, ...)  colsum f32 8192 | partial f32 65536
  char* base = (char*)d_ws;
  float2* cand   = (float2*)base;
  f16*   q16     = (f16*)base;
  f16*   w16     = (f16*)(base + (size_t)32 * 1024 * 1024);
  int*   counts  = (int*)(base + (size_t)112 * 1024 * 1024);
  unsigned long long* maskbits =
      (unsigned long long*)(base + (size_t)114 * 1024 * 1024);
  f16*   qp16    = (f16*)(base + (size_t)128 * 1024 * 1024);
  f16*   k16     = (f16*)(base + (size_t)160 * 1024 * 1024);
  float* colsum  = (float*)(base + (size_t)192 * 1024 * 1024);
  float* partial = colsum + 8192;

  prep1_kernel<<<19712, 256, 0, stream>>>(queries, W, (const int4*)mask, values,
                                          q16, w16, maskbits, partial);
  prep2_kernel<<<16416, 256, 0, stream>>>(keys, partial, k16, colsum);
  gemm_qproj<<<2048, 256, 0, stream>>>(q16, w16, qp16);
  gemm_scores<<<4096, 256, 0, stream>>>(qp16, k16, maskbits, cand, counts);
  topk_kernel<<<2048, 512, 0, stream>>>(cand, counts, values, colsum, out);
}

// Round 10
// 301.108 us; speedup vs baseline: 1.1624x; 1.1624x over previous
//
#include <hip/hip_runtime.h>
#include <math.h>

#define BATCH 8
#define SEQ   2048      // LQ == LK
#define DIM   1024      // DQ == DK == DV
#define TOPK  64
#define NEGMASK -1e30f
#define CAND_THRESH 16.0f   // drop alpha <= e^-16: g <= 1.1e-7, invisible at 2e-3
#define CAP 28              // candidate slots per [row][tile][half]

typedef _Float16 f16;
typedef _Float16 f16x8 __attribute__((ext_vector_type(8)));
typedef float f32x4 __attribute__((ext_vector_type(4)));

// async global->LDS, 16B per lane; LDS dest is wave-uniform base + lane*16.
__device__ __forceinline__ void async_load16(const void* g, void* l) {
  __builtin_amdgcn_global_load_lds(
      (const __attribute__((address_space(1))) void*)g,
      (__attribute__((address_space(3))) void*)l, 16, 0, 0);
}

// ---------------- prep1: cvt(Q), cvt(W), pack_mask, colsum_partial ----------------
// mask-bit layout: word (grp*4 + j), bit l <-> column grp*256 + 4*l + j.
__global__ __launch_bounds__(256) void prep1_kernel(
    const float* __restrict__ queries, const float* __restrict__ W,
    const int4* __restrict__ mask4, const float* __restrict__ values,
    f16* __restrict__ q16, f16* __restrict__ w16,
    unsigned long long* __restrict__ mb, float* __restrict__ partial) {
  const int blk = blockIdx.x;
  if (blk < 16384) {                       // cvt queries (16M elems)
    int i = (blk * 256 + threadIdx.x) * 4;
    float4 v = *(const float4*)(queries + i);
    union { f16 h[4]; uint2 u; } pk;
    pk.h[0] = (f16)v.x; pk.h[1] = (f16)v.y; pk.h[2] = (f16)v.z; pk.h[3] = (f16)v.w;
    *(uint2*)(q16 + i) = pk.u;
  } else if (blk < 17408) {                // cvt W (1M elems)
    int i = ((blk - 16384) * 256 + threadIdx.x) * 4;
    float4 v = *(const float4*)(W + i);
    union { f16 h[4]; uint2 u; } pk;
    pk.h[0] = (f16)v.x; pk.h[1] = (f16)v.y; pk.h[2] = (f16)v.z; pk.h[3] = (f16)v.w;
    *(uint2*)(w16 + i) = pk.u;
  } else if (blk < 19456) {                // pack_mask (2048 virtual blocks)
    const int bid = blk - 17408;
    const int wave = threadIdx.x >> 6, lane = threadIdx.x & 63;
    const size_t nGrp = (size_t)16384 * 8;
    for (size_t g = (size_t)bid * 8 + wave * 2; g < nGrp; g += 2048 * 8) {
      int4 v0 = mask4[g * 64 + lane];
      int4 v1 = mask4[(g + 1) * 64 + lane];
      unsigned long long a0 = __ballot(v0.x != 0);
      unsigned long long a1 = __ballot(v0.y != 0);
      unsigned long long a2 = __ballot(v0.z != 0);
      unsigned long long a3 = __ballot(v0.w != 0);
      unsigned long long b0 = __ballot(v1.x != 0);
      unsigned long long b1 = __ballot(v1.y != 0);
      unsigned long long b2 = __ballot(v1.z != 0);
      unsigned long long b3 = __ballot(v1.w != 0);
      if (lane == 0) {
        mb[g * 4 + 0] = a0; mb[g * 4 + 1] = a1;
        mb[g * 4 + 2] = a2; mb[g * 4 + 3] = a3;
        mb[g * 4 + 4] = b0; mb[g * 4 + 5] = b1;
        mb[g * 4 + 6] = b2; mb[g * 4 + 7] = b3;
      }
    }
  } else {                                 // colsum_partial (1024 virtual blocks)
    const int bid = blk - 19456;           // tc(32) x b(8) x dg(4)
    int tc = bid >> 5;
    int b  = (bid >> 2) & 7;
    int dg = bid & 3;
    int d  = dg * 256 + threadIdx.x;
    const float* vp = values + ((size_t)b * SEQ + (size_t)tc * 64) * DIM + d;
    float s = 0.f;
    #pragma unroll 8
    for (int t = 0; t < 64; ++t) s += vp[(size_t)t * DIM];
    partial[((size_t)tc * BATCH + b) * DIM + d] = s;
  }
}

// ---------------- prep2: cvt(keys), colsum_reduce ----------------
__global__ __launch_bounds__(256) void prep2_kernel(
    const float* __restrict__ keys, const float* __restrict__ partial,
    f16* __restrict__ k16, float* __restrict__ colsum) {
  const int blk = blockIdx.x;
  if (blk < 16384) {                       // cvt keys (16M elems)
    int i = (blk * 256 + threadIdx.x) * 4;
    float4 v = *(const float4*)(keys + i);
    union { f16 h[4]; uint2 u; } pk;
    pk.h[0] = (f16)v.x; pk.h[1] = (f16)v.y; pk.h[2] = (f16)v.z; pk.h[3] = (f16)v.w;
    *(uint2*)(k16 + i) = pk.u;
  } else {                                 // colsum_reduce (32 virtual blocks)
    int idx = (blk - 16384) * 256 + threadIdx.x;   // 8192
    float s = 0.f;
    #pragma unroll
    for (int tc = 0; tc < 32; ++tc) s += partial[(size_t)tc * 8192 + idx];
    colsum[idx] = s;
  }
}

// ---------------- MFMA bt-GEMM core (fp16, counted-vmcnt 2-phase, 128²) ----------------
// r8 geometry (best measured): 128x128 tile, 4 waves (2Mx2N, 64x64/wave),
// BK=32, 32 KB LDS dbuf, launch_bounds(256,3).
// NEW fencing (T4): never vmcnt(0) in steady state. Per step:
//   STAGE(nxt) ; vmcnt(4) [prev step's loads landed, issued ~1 step ago]
//   s_barrier  [all waves certified their own prev loads -> RAW safe]
//   ds_read(cur) ; MFMA
//   s_barrier  [reads retired -> next step's STAGE overwrite is WAR safe]
// Tail step stages nothing -> vmcnt(0). Empty asm "memory" fences pin the
// C++ LDS reads inside the barrier pair. Slot XOR-swizzle as r5-r8
// (SQ_LDS_BANK_CONFLICT == 0 verified).

#define STAGEK(KOFF, BUF)                                                   \
  async_load16(srcA0 + (KOFF), smA + (BUF) * 8192 + wave * 2048);           \
  async_load16(srcA1 + (KOFF), smA + (BUF) * 8192 + wave * 2048 + 1024);    \
  async_load16(srcB0 + (KOFF), smB + (BUF) * 8192 + wave * 2048);           \
  async_load16(srcB1 + (KOFF), smB + (BUF) * 8192 + wave * 2048 + 1024);

#define GEMM_PROLOGUE(APTR, BPTR)                                           \
  const int tid = threadIdx.x;                                              \
  const int wave = tid >> 6, lane = tid & 63;                               \
  const int wm = (wave >> 1) * 64, wn = (wave & 1) * 64;                    \
  const int r0 = wave * 32 + (lane >> 2);                                   \
  const int c16 = (lane & 3) ^ ((r0 >> 1) & 3);                            \
  const f16* srcA0 = (APTR) + (size_t)(m0 + r0) * DIM + c16 * 8;           \
  const f16* srcA1 = (APTR) + (size_t)(m0 + r0 + 16) * DIM + c16 * 8;      \
  const f16* srcB0 = (BPTR) + (size_t)(n0 + r0) * DIM + c16 * 8;           \
  const f16* srcB1 = (BPTR) + (size_t)(n0 + r0 + 16) * DIM + c16 * 8;      \
  int offA[4], offB[4];                                                     \
  _Pragma("unroll")                                                         \
  for (int i = 0; i < 4; ++i) {                                             \
    int r = wm + i * 16 + (lane & 15);                                      \
    offA[i] = r * 64 + ((lane >> 4) ^ ((r >> 1) & 3)) * 16;                 \
    int rn = wn + i * 16 + (lane & 15);                                     \
    offB[i] = rn * 64 + ((lane >> 4) ^ ((rn >> 1) & 3)) * 16;               \
  }                                                                         \
  f32x4 acc[4][4];                                                          \
  _Pragma("unroll")                                                         \
  for (int i = 0; i < 4; ++i)                                               \
    _Pragma("unroll")                                                       \
    for (int j = 0; j < 4; ++j)                                             \
      acc[i][j] = (f32x4){0.f, 0.f, 0.f, 0.f};                              \
  STAGEK(0, 0)                                                              \
  int cur = 0;                                                              \
  for (int k0 = 0; k0 < DIM; k0 += 32) {                                    \
    const int nxt = cur ^ 1;                                                \
    if (k0 + 32 < DIM) {                                                    \
      STAGEK(k0 + 32, nxt)                                                  \
      asm volatile("s_waitcnt vmcnt(4)" ::: "memory");                      \
    } else {                                                                \
      asm volatile("s_waitcnt vmcnt(0)" ::: "memory");                      \
    }                                                                       \
    __builtin_amdgcn_s_barrier();                                           \
    asm volatile("" ::: "memory");                                          \
    f16x8 af[4], bf[4];                                                     \
    _Pragma("unroll")                                                       \
    for (int i = 0; i < 4; ++i) {                                           \
      af[i] = *(const f16x8*)(smA + cur * 8192 + offA[i]);                  \
      bf[i] = *(const f16x8*)(smB + cur * 8192 + offB[i]);                  \
    }                                                                       \
    _Pragma("unroll")                                                       \
    for (int i = 0; i < 4; ++i)                                             \
      _Pragma("unroll")                                                     \
      for (int j = 0; j < 4; ++j)                                           \
        acc[i][j] = __builtin_amdgcn_mfma_f32_16x16x32_f16(                 \
            af[i], bf[j], acc[i][j], 0, 0, 0);                              \
    asm volatile("" ::: "memory");                                          \
    __builtin_amdgcn_s_barrier();                                           \
    cur = nxt;                                                              \
  }

__global__ __launch_bounds__(256, 3) void gemm_qproj(
    const f16* __restrict__ A, const f16* __restrict__ Bw,
    f16* __restrict__ C) {
  __shared__ __align__(128) char smA[16384];
  __shared__ __align__(128) char smB[16384];
  // XCD-swizzled 1D grid: 1024 blocks, 8 n-tiles x 128 m-tiles
  const int swz = (blockIdx.x & 7) * 128 + (blockIdx.x >> 3);
  const int m0 = (swz >> 3) * 128;
  const int n0 = (swz & 7) * 128;
  GEMM_PROLOGUE(A, Bw)
  // C/D layout (verified r2+): col = lane&15, row = (lane>>4)*4 + reg
  const int cr = m0 + wm + (lane >> 4) * 4;
  const int cc = n0 + wn + (lane & 15);
  #pragma unroll
  for (int i = 0; i < 4; ++i)
    #pragma unroll
    for (int j = 0; j < 4; ++j)
      #pragma unroll
      for (int reg = 0; reg < 4; ++reg)
        C[(size_t)(cr + i * 16 + reg) * DIM + cc + j * 16] = (f16)acc[i][j][reg];
}

// scores GEMM + fused mask + per-row tile-max + candidate emission.
// Emits, per [row][128-col tile][64-col half], candidates
// {s > tilemax(row,128 cols) - 16} (superset of global {s > mv-16}).
__global__ __launch_bounds__(256, 3) void gemm_scores(
    const f16* __restrict__ QP, const f16* __restrict__ K16,
    const unsigned long long* __restrict__ maskbits,  // [16384][8grp][4jw]
    float2* __restrict__ cand,                        // [16384][32][CAP]
    int* __restrict__ counts) {                       // [16384][32]
  __shared__ __align__(128) char smA[16384];
  __shared__ __align__(128) char smB[16384];
  // XCD-swizzled 1D grid: 2048 blocks; XCD x gets m-band = batch x.
  const int swz = (blockIdx.x & 7) * 256 + (blockIdx.x >> 3);
  const int m0 = (swz >> 4) * 128;     // global flat q-row tile
  const int n0 = (swz & 15) * 128;     // t col within batch
  const int b  = m0 >> 11;
  const f16* Bk = K16 + (size_t)b * SEQ * DIM;
  GEMM_PROLOGUE(QP, Bk)

  const int g  = lane >> 4;    // 16-lane group = 4-row band
  const int lc = lane & 15;    // col within 16

  // apply mask bits: word = grp*4 + (lc&3), bit = basebit + j*4 + (lc>>2)
  const int grp = (n0 + wn) >> 8;
  const int basebit = ((n0 + wn) & 255) >> 2;
  #pragma unroll
  for (int i = 0; i < 4; ++i)
    #pragma unroll
    for (int reg = 0; reg < 4; ++reg) {
      const int r = wm + i * 16 + g * 4 + reg;
      const unsigned long long mw =
          maskbits[(size_t)(m0 + r) * 32 + grp * 4 + (lc & 3)];
      #pragma unroll
      for (int j = 0; j < 4; ++j)
        if (!((mw >> (basebit + j * 4 + (lc >> 2))) & 1ull))
          acc[i][j][reg] = NEGMASK;
    }

  // per-row max over this wave's 64 cols -> LDS halfmax[128][2]
  float* hm = (float*)smA;   // LDS free after final K-loop barrier
  #pragma unroll
  for (int i = 0; i < 4; ++i)
    #pragma unroll
    for (int reg = 0; reg < 4; ++reg) {
      const int r = wm + i * 16 + g * 4 + reg;
      float m4 = fmaxf(fmaxf(acc[i][0][reg], acc[i][1][reg]),
                       fmaxf(acc[i][2][reg], acc[i][3][reg]));
      #pragma unroll
      for (int off = 8; off >= 1; off >>= 1) m4 = fmaxf(m4, __shfl_xor(m4, off));
      if (lc == 0) hm[r * 2 + (wn >> 6)] = m4;
    }
  __syncthreads();

  // ballot-compact candidates (deterministic: slot = running popcount)
  const int pairbase = (n0 >> 7) * 2 + (wn >> 6);   // tile*2 + half
  #pragma unroll
  for (int i = 0; i < 4; ++i)
    #pragma unroll
    for (int reg = 0; reg < 4; ++reg) {
      const int r = wm + i * 16 + g * 4 + reg;
      const float tm = fmaxf(hm[r * 2], hm[r * 2 + 1]);
      const float thresh = fmaxf(tm - CAND_THRESH, -1e29f);
      float2* slot = cand + ((size_t)(m0 + r) * 32 + pairbase) * CAP;
      int cnt = 0;
      #pragma unroll
      for (int j = 0; j < 4; ++j) {
        const float s = acc[i][j][reg];
        const bool c = s > thresh;
        const unsigned long long bal = __ballot(c);
        const int seg = (int)((bal >> (g * 16)) & 0xFFFFull);
        const int pos = cnt + __popc(seg & ((1 << lc) - 1));
        if (c && pos < CAP) {
          float2 e; e.x = s; e.y = __int_as_float(n0 + wn + j * 16 + lc);
          slot[pos] = e;
        }
        cnt += __popc(seg);
      }
      if (lc == 0) counts[(size_t)(m0 + r) * 32 + pairbase] = cnt < CAP ? cnt : CAP;
    }
}

// ---------------- topk from candidate lists (unchanged) ----------------
__global__ __launch_bounds__(512) void topk_kernel(
    const float2* __restrict__ cand,       // [16384][32][CAP]
    const int*    __restrict__ counts,     // [16384][32]
    const float*  __restrict__ values,     // [8][2048][1024]
    const float*  __restrict__ colsum,     // [8][1024]
    float* __restrict__ out)               // [16384][1024]
{
  __shared__ float ssc[8][128];
  __shared__ int   sidx[8][128];
  const int wave = threadIdx.x >> 6;
  const int lane = threadIdx.x & 63;
  const int grow = blockIdx.x * 8 + wave;      // global flat q-row
  const int b    = grow >> 11;
  float* msc = ssc[wave];
  int*   mix = sidx[wave];

  int cnt_p = 0;
  if (lane < 32) cnt_p = counts[(size_t)grow * 32 + lane];
  const float2* myslots = cand + ((size_t)grow * 32 + lane) * CAP;

  // pass 1: global row max over candidates
  float mv = -3e38f;
  for (int k = 0; k < cnt_p; ++k) mv = fmaxf(mv, myslots[k].x);
  #pragma unroll
  for (int off = 32; off > 0; off >>= 1) mv = fmaxf(mv, __shfl_xor(mv, off));
  const bool dead = (mv <= -1e29f);   // fully-masked row -> uniform softmax

  float total_g = 0.f;
  f32x4 oacc[4];
  #pragma unroll
  for (int j = 0; j < 4; ++j) oacc[j] = (f32x4){0.f, 0.f, 0.f, 0.f};
  const float* vbase = values + (size_t)b * SEQ * DIM;

  if (!dead) {
    const float thresh = mv - CAND_THRESH;
    // pass 2: filter count + Z partial
    int f = 0; float zp = 0.f;
    for (int k = 0; k < cnt_p; ++k) {
      float s = myslots[k].x;
      if (s > thresh) { ++f; zp += __expf(s - mv); }
    }
    // prefix over 64 lanes for deterministic compaction order
    int incl = f;
    #pragma unroll
    for (int off = 1; off < 64; off <<= 1) {
      int t = __shfl_up(incl, off);
      if (lane >= off) incl += t;
    }
    const int base = incl - f;
    const int F = __shfl(incl, 63);
    #pragma unroll
    for (int off = 32; off > 0; off >>= 1) zp += __shfl_xor(zp, off);
    const float Z = zp;
    // compact filtered candidates to LDS (order: (pair, slot))
    int w = 0;
    for (int k = 0; k < cnt_p; ++k) {
      float2 cv = myslots[k];
      if (cv.x > thresh) {
        int p = base + w;
        if (p < 128) { msc[p] = cv.x; mix[p] = __float_as_int(cv.y); }
        ++w;
      }
    }
    asm volatile("s_waitcnt lgkmcnt(0)" ::: "memory");

    if (F <= TOPK) {
      // common path: filtered set == significant top-k members
      for (int c = 0; c < F; ++c) {
        float g = expm1f(__expf(msc[c] - mv) / Z);
        total_g += g;
        const float* vrow = vbase + (size_t)mix[c] * DIM;
        #pragma unroll
        for (int j = 0; j < 4; ++j) {
          f32x4 v = *(const f32x4*)(vrow + j * 256 + lane * 4);
          #pragma unroll
          for (int e = 0; e < 4; ++e) oacc[j][e] = fmaf(g, v[e], oacc[j][e]);
        }
      }
    } else {
      // rare path: exact top-64 by (score desc, idx asc) from the list
      const int nlist = F < 128 ? F : 128;
      for (int itk = 0; itk < TOPK; ++itk) {
        float bv = -3e38f; int bi = 1 << 30; int bsl = -1;
        #pragma unroll
        for (int h = 0; h < 2; ++h) {
          int sl = lane + h * 64;
          if (sl < nlist) {
            float v = msc[sl]; int id = mix[sl];
            if (v > bv || (v == bv && id < bi)) { bv = v; bi = id; bsl = sl; }
          }
        }
        #pragma unroll
        for (int off = 32; off > 0; off >>= 1) {
          float ov = __shfl_xor(bv, off);
          int   oi = __shfl_xor(bi, off);
          int   os = __shfl_xor(bsl, off);
          if (ov > bv || (ov == bv && oi < bi)) { bv = ov; bi = oi; bsl = os; }
        }
        if (bv <= -1e29f) break;
        float g = expm1f(__expf(bv - mv) / Z);
        total_g += g;
        const float* vrow = vbase + (size_t)bi * DIM;
        #pragma unroll
        for (int j = 0; j < 4; ++j) {
          f32x4 v = *(const f32x4*)(vrow + j * 256 + lane * 4);
          #pragma unroll
          for (int e = 0; e < 4; ++e) oacc[j][e] = fmaf(g, v[e], oacc[j][e]);
        }
        if (lane == 0) msc[bsl] = -3e38f;
        asm volatile("s_waitcnt lgkmcnt(0)" ::: "memory");
      }
    }
  }

  // out = (colsum + sum g*v) / (2048 + sum g)
  const float inv = 1.0f / (2048.0f + total_g);
  const float* cs = colsum + (size_t)b * DIM;
  float* orow = out + (size_t)grow * DIM;
  #pragma unroll
  for (int j = 0; j < 4; ++j) {
    f32x4 c = *(const f32x4*)(cs + j * 256 + lane * 4);
    f32x4 o;
    #pragma unroll
    for (int e = 0; e < 4; ++e) o[e] = (c[e] + oacc[j][e]) * inv;
    *(f32x4*)(orow + j * 256 + lane * 4) = o;
  }
}

extern "C" void kernel_launch(void* const* d_in, const int* in_sizes, int n_in,
                              void* d_out, int out_size, void* d_ws, size_t ws_size,
                              hipStream_t stream) {
  const float* queries = (const float*)d_in[0];
  const float* keys    = (const float*)d_in[1];
  const float* values  = (const float*)d_in[2];
  const int*   mask    = (const int*)d_in[3];
  const float* W       = (const float*)d_in[4];
  float* out = (float*)d_out;

  // ws layout (bytes), total 192 MB (within proven footprint):
  //   [0, 112M)    cand float2[16384][32][28]
  //       q16 aliases [0, 32M)   (dead before gemm_scores)
  //       w16 aliases [32M, 34M) (dead before gemm_scores)
  //   [112M, 114M) counts int[16384][32]
  //   [114M, 118M) maskbits u64[16384][32]
  //   [118M, 118M+32K) colsum f32 8192
  //   [119M, 120M) partial f32 [32][8192]
  //   [128M, 160M) qp16 f16 [16384][1024]
  //   [160M, 192M) k16  f16 [8][2048][1024]
  char* base = (char*)d_ws;
  float2* cand   = (float2*)base;
  f16*   q16     = (f16*)base;
  f16*   w16     = (f16*)(base + (size_t)32 * 1024 * 1024);
  int*   counts  = (int*)(base + (size_t)112 * 1024 * 1024);
  unsigned long long* maskbits =
      (unsigned long long*)(base + (size_t)114 * 1024 * 1024);
  float* colsum  = (float*)(base + (size_t)118 * 1024 * 1024);
  float* partial = (float*)(base + (size_t)119 * 1024 * 1024);
  f16*   qp16    = (f16*)(base + (size_t)128 * 1024 * 1024);
  f16*   k16     = (f16*)(base + (size_t)160 * 1024 * 1024);

  prep1_kernel<<<20480, 256, 0, stream>>>(queries, W, (const int4*)mask, values,
                                          q16, w16, maskbits, partial);
  prep2_kernel<<<16416, 256, 0, stream>>>(keys, partial, k16, colsum);
  gemm_qproj<<<1024, 256, 0, stream>>>(q16, w16, qp16);
  gemm_scores<<<2048, 256, 0, stream>>>(qp16, k16, maskbits, cand, counts);
  topk_kernel<<<2048, 512, 0, stream>>>(cand, counts, values, colsum, out);
}

// Round 12
// 300.474 us; speedup vs baseline: 1.1649x; 1.0021x over previous
//
#include <hip/hip_runtime.h>
#include <math.h>

#define BATCH 8
#define SEQ   2048      // LQ == LK
#define DIM   1024      // DQ == DK == DV
#define TOPK  64
#define NEGMASK -1e30f
#define CAND_THRESH 16.0f   // drop alpha <= e^-16: g <= 1.1e-7, invisible at 2e-3
#define CAP 28              // candidate slots per [row][tile][half]

typedef _Float16 f16;
typedef _Float16 f16x8 __attribute__((ext_vector_type(8)));
typedef float f32x4 __attribute__((ext_vector_type(4)));

// async global->LDS, 16B per lane; LDS dest is wave-uniform base + lane*16.
__device__ __forceinline__ void async_load16(const void* g, void* l) {
  __builtin_amdgcn_global_load_lds(
      (const __attribute__((address_space(1))) void*)g,
      (__attribute__((address_space(3))) void*)l, 16, 0, 0);
}

// ---------------- prep: cvt(Q), cvt(keys), cvt(W), pack_mask, colsum_partial ----------------
// All branches are r10's exact proven bodies; block-range dispatch.
// mask-bit layout: word (grp*4 + j), bit l <-> column grp*256 + 4*l + j.
__global__ __launch_bounds__(256) void prep_kernel(
    const float* __restrict__ queries, const float* __restrict__ keys,
    const float* __restrict__ W,
    const int4* __restrict__ mask4, const float* __restrict__ values,
    f16* __restrict__ q16, f16* __restrict__ k16, f16* __restrict__ w16,
    unsigned long long* __restrict__ mb, float* __restrict__ partial) {
  const int blk = blockIdx.x;
  if (blk < 16384) {                       // cvt queries (16M elems)
    int i = (blk * 256 + threadIdx.x) * 4;
    float4 v = *(const float4*)(queries + i);
    union { f16 h[4]; uint2 u; } pk;
    pk.h[0] = (f16)v.x; pk.h[1] = (f16)v.y; pk.h[2] = (f16)v.z; pk.h[3] = (f16)v.w;
    *(uint2*)(q16 + i) = pk.u;
  } else if (blk < 32768) {                // cvt keys (16M elems)
    int i = ((blk - 16384) * 256 + threadIdx.x) * 4;
    float4 v = *(const float4*)(keys + i);
    union { f16 h[4]; uint2 u; } pk;
    pk.h[0] = (f16)v.x; pk.h[1] = (f16)v.y; pk.h[2] = (f16)v.z; pk.h[3] = (f16)v.w;
    *(uint2*)(k16 + i) = pk.u;
  } else if (blk < 33792) {                // cvt W (1M elems)
    int i = ((blk - 32768) * 256 + threadIdx.x) * 4;
    float4 v = *(const float4*)(W + i);
    union { f16 h[4]; uint2 u; } pk;
    pk.h[0] = (f16)v.x; pk.h[1] = (f16)v.y; pk.h[2] = (f16)v.z; pk.h[3] = (f16)v.w;
    *(uint2*)(w16 + i) = pk.u;
  } else if (blk < 35840) {                // pack_mask (2048 virtual blocks, r10 2-deep)
    const int bid = blk - 33792;
    const int wave = threadIdx.x >> 6, lane = threadIdx.x & 63;
    const size_t nGrp = (size_t)16384 * 8;
    for (size_t g = (size_t)bid * 8 + wave * 2; g < nGrp; g += 2048 * 8) {
      int4 v0 = mask4[g * 64 + lane];
      int4 v1 = mask4[(g + 1) * 64 + lane];
      unsigned long long a0 = __ballot(v0.x != 0);
      unsigned long long a1 = __ballot(v0.y != 0);
      unsigned long long a2 = __ballot(v0.z != 0);
      unsigned long long a3 = __ballot(v0.w != 0);
      unsigned long long b0 = __ballot(v1.x != 0);
      unsigned long long b1 = __ballot(v1.y != 0);
      unsigned long long b2 = __ballot(v1.z != 0);
      unsigned long long b3 = __ballot(v1.w != 0);
      if (lane == 0) {
        mb[g * 4 + 0] = a0; mb[g * 4 + 1] = a1;
        mb[g * 4 + 2] = a2; mb[g * 4 + 3] = a3;
        mb[g * 4 + 4] = b0; mb[g * 4 + 5] = b1;
        mb[g * 4 + 6] = b2; mb[g * 4 + 7] = b3;
      }
    }
  } else {                                 // colsum_partial (1024 virtual blocks)
    const int bid = blk - 35840;           // tc(32) x b(8) x dg(4)
    int tc = bid >> 5;
    int b  = (bid >> 2) & 7;
    int dg = bid & 3;
    int d  = dg * 256 + threadIdx.x;
    const float* vp = values + ((size_t)b * SEQ + (size_t)tc * 64) * DIM + d;
    float s = 0.f;
    #pragma unroll 8
    for (int t = 0; t < 64; ++t) s += vp[(size_t)t * DIM];
    partial[((size_t)tc * BATCH + b) * DIM + d] = s;
  }
}

// ---------------- MFMA bt-GEMM core (fp16, counted-vmcnt 2-phase, 128²) ----------------
// r10 core, byte-identical (measured: 110 µs scores, MfmaUtil 26.7%, 0 conflicts).
//   STAGE(nxt) ; vmcnt(4) [prev step's loads landed]
//   s_barrier ; ds_read(cur)+MFMA ; s_barrier.  Tail: vmcnt(0).
// Slot XOR-swizzle (rule #21): linear LDS dest, inverse-swizzled global src,
// swizzled ds_read_b128.

#define STAGEK(KOFF, BUF)                                                   \
  async_load16(srcA0 + (KOFF), smA + (BUF) * 8192 + wave * 2048);           \
  async_load16(srcA1 + (KOFF), smA + (BUF) * 8192 + wave * 2048 + 1024);    \
  async_load16(srcB0 + (KOFF), smB + (BUF) * 8192 + wave * 2048);           \
  async_load16(srcB1 + (KOFF), smB + (BUF) * 8192 + wave * 2048 + 1024);

#define GEMM_PROLOGUE(APTR, BPTR)                                           \
  const int tid = threadIdx.x;                                              \
  const int wave = tid >> 6, lane = tid & 63;                               \
  const int wm = (wave >> 1) * 64, wn = (wave & 1) * 64;                    \
  const int r0 = wave * 32 + (lane >> 2);                                   \
  const int c16 = (lane & 3) ^ ((r0 >> 1) & 3);                            \
  const f16* srcA0 = (APTR) + (size_t)(m0 + r0) * DIM + c16 * 8;           \
  const f16* srcA1 = (APTR) + (size_t)(m0 + r0 + 16) * DIM + c16 * 8;      \
  const f16* srcB0 = (BPTR) + (size_t)(n0 + r0) * DIM + c16 * 8;           \
  const f16* srcB1 = (BPTR) + (size_t)(n0 + r0 + 16) * DIM + c16 * 8;      \
  int offA[4], offB[4];                                                     \
  _Pragma("unroll")                                                         \
  for (int i = 0; i < 4; ++i) {                                             \
    int r = wm + i * 16 + (lane & 15);                                      \
    offA[i] = r * 64 + ((lane >> 4) ^ ((r >> 1) & 3)) * 16;                 \
    int rn = wn + i * 16 + (lane & 15);                                     \
    offB[i] = rn * 64 + ((lane >> 4) ^ ((rn >> 1) & 3)) * 16;               \
  }                                                                         \
  f32x4 acc[4][4];                                                          \
  _Pragma("unroll")                                                         \
  for (int i = 0; i < 4; ++i)                                               \
    _Pragma("unroll")                                                       \
    for (int j = 0; j < 4; ++j)                                             \
      acc[i][j] = (f32x4){0.f, 0.f, 0.f, 0.f};                              \
  STAGEK(0, 0)                                                              \
  int cur = 0;                                                              \
  for (int k0 = 0; k0 < DIM; k0 += 32) {                                    \
    const int nxt = cur ^ 1;                                                \
    if (k0 + 32 < DIM) {                                                    \
      STAGEK(k0 + 32, nxt)                                                  \
      asm volatile("s_waitcnt vmcnt(4)" ::: "memory");                      \
    } else {                                                                \
      asm volatile("s_waitcnt vmcnt(0)" ::: "memory");                      \
    }                                                                       \
    __builtin_amdgcn_s_barrier();                                           \
    asm volatile("" ::: "memory");                                          \
    f16x8 af[4], bf[4];                                                     \
    _Pragma("unroll")                                                       \
    for (int i = 0; i < 4; ++i) {                                           \
      af[i] = *(const f16x8*)(smA + cur * 8192 + offA[i]);                  \
      bf[i] = *(const f16x8*)(smB + cur * 8192 + offB[i]);                  \
    }                                                                       \
    _Pragma("unroll")                                                       \
    for (int i = 0; i < 4; ++i)                                             \
      _Pragma("unroll")                                                     \
      for (int j = 0; j < 4; ++j)                                           \
        acc[i][j] = __builtin_amdgcn_mfma_f32_16x16x32_f16(                 \
            af[i], bf[j], acc[i][j], 0, 0, 0);                              \
    asm volatile("" ::: "memory");                                          \
    __builtin_amdgcn_s_barrier();                                           \
    cur = nxt;                                                              \
  }

// gemm_qproj + fused colsum_reduce (blocks >= 1024; r10 reduce body)
__global__ __launch_bounds__(256, 3) void gemm_qproj(
    const f16* __restrict__ A, const f16* __restrict__ Bw,
    f16* __restrict__ C,
    const float* __restrict__ partial, float* __restrict__ colsum) {
  __shared__ __align__(128) char smA[16384];
  __shared__ __align__(128) char smB[16384];
  if (blockIdx.x >= 1024) {                // colsum_reduce (32 virtual blocks)
    int idx = ((int)blockIdx.x - 1024) * 256 + threadIdx.x;   // 8192
    float s = 0.f;
    #pragma unroll
    for (int tc = 0; tc < 32; ++tc) s += partial[(size_t)tc * 8192 + idx];
    colsum[idx] = s;
    return;
  }
  // XCD-swizzled 1D grid: 1024 blocks, 8 n-tiles x 128 m-tiles
  const int swz = ((int)blockIdx.x & 7) * 128 + ((int)blockIdx.x >> 3);
  const int m0 = (swz >> 3) * 128;
  const int n0 = (swz & 7) * 128;
  GEMM_PROLOGUE(A, Bw)
  // C/D layout (verified r2+): col = lane&15, row = (lane>>4)*4 + reg
  const int cr = m0 + wm + (lane >> 4) * 4;
  const int cc = n0 + wn + (lane & 15);
  #pragma unroll
  for (int i = 0; i < 4; ++i)
    #pragma unroll
    for (int j = 0; j < 4; ++j)
      #pragma unroll
      for (int reg = 0; reg < 4; ++reg)
        C[(size_t)(cr + i * 16 + reg) * DIM + cc + j * 16] = (f16)acc[i][j][reg];
}

// scores GEMM + fused mask + per-row tile-max + candidate emission (r10 verbatim).
// Emits, per [row][128-col tile][64-col half], candidates
// {s > tilemax(row,128 cols) - 16} (superset of global {s > mv-16}).
__global__ __launch_bounds__(256, 3) void gemm_scores(
    const f16* __restrict__ QP, const f16* __restrict__ K16,
    const unsigned long long* __restrict__ maskbits,  // [16384][8grp][4jw]
    float2* __restrict__ cand,                        // [16384][32][CAP]
    int* __restrict__ counts) {                       // [16384][32]
  __shared__ __align__(128) char smA[16384];
  __shared__ __align__(128) char smB[16384];
  // XCD-swizzled 1D grid: 2048 blocks; XCD x gets m-band = batch x.
  const int swz = ((int)blockIdx.x & 7) * 256 + ((int)blockIdx.x >> 3);
  const int m0 = (swz >> 4) * 128;     // global flat q-row tile
  const int n0 = (swz & 15) * 128;     // t col within batch
  const int b  = m0 >> 11;
  const f16* Bk = K16 + (size_t)b * SEQ * DIM;
  GEMM_PROLOGUE(QP, Bk)

  const int g  = lane >> 4;    // 16-lane group = 4-row band
  const int lc = lane & 15;    // col within 16

  // apply mask bits: word = grp*4 + (lc&3), bit = basebit + j*4 + (lc>>2)
  const int grp = (n0 + wn) >> 8;
  const int basebit = ((n0 + wn) & 255) >> 2;
  #pragma unroll
  for (int i = 0; i < 4; ++i)
    #pragma unroll
    for (int reg = 0; reg < 4; ++reg) {
      const int r = wm + i * 16 + g * 4 + reg;
      const unsigned long long mw =
          maskbits[(size_t)(m0 + r) * 32 + grp * 4 + (lc & 3)];
      #pragma unroll
      for (int j = 0; j < 4; ++j)
        if (!((mw >> (basebit + j * 4 + (lc >> 2))) & 1ull))
          acc[i][j][reg] = NEGMASK;
    }

  // per-row max over this wave's 64 cols -> LDS halfmax[128][2]
  float* hm = (float*)smA;   // LDS free after final K-loop barrier
  #pragma unroll
  for (int i = 0; i < 4; ++i)
    #pragma unroll
    for (int reg = 0; reg < 4; ++reg) {
      const int r = wm + i * 16 + g * 4 + reg;
      float m4 = fmaxf(fmaxf(acc[i][0][reg], acc[i][1][reg]),
                       fmaxf(acc[i][2][reg], acc[i][3][reg]));
      #pragma unroll
      for (int off = 8; off >= 1; off >>= 1) m4 = fmaxf(m4, __shfl_xor(m4, off));
      if (lc == 0) hm[r * 2 + (wn >> 6)] = m4;
    }
  __syncthreads();

  // ballot-compact candidates (deterministic: slot = running popcount)
  const int pairbase = (n0 >> 7) * 2 + (wn >> 6);   // tile*2 + half
  #pragma unroll
  for (int i = 0; i < 4; ++i)
    #pragma unroll
    for (int reg = 0; reg < 4; ++reg) {
      const int r = wm + i * 16 + g * 4 + reg;
      const float tm = fmaxf(hm[r * 2], hm[r * 2 + 1]);
      const float thresh = fmaxf(tm - CAND_THRESH, -1e29f);
      float2* slot = cand + ((size_t)(m0 + r) * 32 + pairbase) * CAP;
      int cnt = 0;
      #pragma unroll
      for (int j = 0; j < 4; ++j) {
        const float s = acc[i][j][reg];
        const bool c = s > thresh;
        const unsigned long long bal = __ballot(c);
        const int seg = (int)((bal >> (g * 16)) & 0xFFFFull);
        const int pos = cnt + __popc(seg & ((1 << lc) - 1));
        if (c && pos < CAP) {
          float2 e; e.x = s; e.y = __int_as_float(n0 + wn + j * 16 + lc);
          slot[pos] = e;
        }
        cnt += __popc(seg);
      }
      if (lc == 0) counts[(size_t)(m0 + r) * 32 + pairbase] = cnt < CAP ? cnt : CAP;
    }
}

// ---------------- topk from candidate lists (r10 verbatim) ----------------
__global__ __launch_bounds__(512) void topk_kernel(
    const float2* __restrict__ cand,       // [16384][32][CAP]
    const int*    __restrict__ counts,     // [16384][32]
    const float*  __restrict__ values,     // [8][2048][1024]
    const float*  __restrict__ colsum,     // [8][1024]
    float* __restrict__ out)               // [16384][1024]
{
  __shared__ float ssc[8][128];
  __shared__ int   sidx[8][128];
  const int wave = threadIdx.x >> 6;
  const int lane = threadIdx.x & 63;
  const int grow = blockIdx.x * 8 + wave;      // global flat q-row
  const int b    = grow >> 11;
  float* msc = ssc[wave];
  int*   mix = sidx[wave];

  int cnt_p = 0;
  if (lane < 32) cnt_p = counts[(size_t)grow * 32 + lane];
  const float2* myslots = cand + ((size_t)grow * 32 + lane) * CAP;

  // pass 1: global row max over candidates
  float mv = -3e38f;
  for (int k = 0; k < cnt_p; ++k) mv = fmaxf(mv, myslots[k].x);
  #pragma unroll
  for (int off = 32; off > 0; off >>= 1) mv = fmaxf(mv, __shfl_xor(mv, off));
  const bool dead = (mv <= -1e29f);   // fully-masked row -> uniform softmax

  float total_g = 0.f;
  f32x4 oacc[4];
  #pragma unroll
  for (int j = 0; j < 4; ++j) oacc[j] = (f32x4){0.f, 0.f, 0.f, 0.f};
  const float* vbase = values + (size_t)b * SEQ * DIM;

  if (!dead) {
    const float thresh = mv - CAND_THRESH;
    // pass 2: filter count + Z partial
    int f = 0; float zp = 0.f;
    for (int k = 0; k < cnt_p; ++k) {
      float s = myslots[k].x;
      if (s > thresh) { ++f; zp += __expf(s - mv); }
    }
    // prefix over 64 lanes for deterministic compaction order
    int incl = f;
    #pragma unroll
    for (int off = 1; off < 64; off <<= 1) {
      int t = __shfl_up(incl, off);
      if (lane >= off) incl += t;
    }
    const int base = incl - f;
    const int F = __shfl(incl, 63);
    #pragma unroll
    for (int off = 32; off > 0; off >>= 1) zp += __shfl_xor(zp, off);
    const float Z = zp;
    // compact filtered candidates to LDS (order: (pair, slot))
    int w = 0;
    for (int k = 0; k < cnt_p; ++k) {
      float2 cv = myslots[k];
      if (cv.x > thresh) {
        int p = base + w;
        if (p < 128) { msc[p] = cv.x; mix[p] = __float_as_int(cv.y); }
        ++w;
      }
    }
    asm volatile("s_waitcnt lgkmcnt(0)" ::: "memory");

    if (F <= TOPK) {
      // common path: filtered set == significant top-k members
      for (int c = 0; c < F; ++c) {
        float g = expm1f(__expf(msc[c] - mv) / Z);
        total_g += g;
        const float* vrow = vbase + (size_t)mix[c] * DIM;
        #pragma unroll
        for (int j = 0; j < 4; ++j) {
          f32x4 v = *(const f32x4*)(vrow + j * 256 + lane * 4);
          #pragma unroll
          for (int e = 0; e < 4; ++e) oacc[j][e] = fmaf(g, v[e], oacc[j][e]);
        }
      }
    } else {
      // rare path: exact top-64 by (score desc, idx asc) from the list
      const int nlist = F < 128 ? F : 128;
      for (int itk = 0; itk < TOPK; ++itk) {
        float bv = -3e38f; int bi = 1 << 30; int bsl = -1;
        #pragma unroll
        for (int h = 0; h < 2; ++h) {
          int sl = lane + h * 64;
          if (sl < nlist) {
            float v = msc[sl]; int id = mix[sl];
            if (v > bv || (v == bv && id < bi)) { bv = v; bi = id; bsl = sl; }
          }
        }
        #pragma unroll
        for (int off = 32; off > 0; off >>= 1) {
          float ov = __shfl_xor(bv, off);
          int   oi = __shfl_xor(bi, off);
          int   os = __shfl_xor(bsl, off);
          if (ov > bv || (ov == bv && oi < bi)) { bv = ov; bi = oi; bsl = os; }
        }
        if (bv <= -1e29f) break;
        float g = expm1f(__expf(bv - mv) / Z);
        total_g += g;
        const float* vrow = vbase + (size_t)bi * DIM;
        #pragma unroll
        for (int j = 0; j < 4; ++j) {
          f32x4 v = *(const f32x4*)(vrow + j * 256 + lane * 4);
          #pragma unroll
          for (int e = 0; e < 4; ++e) oacc[j][e] = fmaf(g, v[e], oacc[j][e]);
        }
        if (lane == 0) msc[bsl] = -3e38f;
        asm volatile("s_waitcnt lgkmcnt(0)" ::: "memory");
      }
    }
  }

  // out = (colsum + sum g*v) / (2048 + sum g)
  const float inv = 1.0f / (2048.0f + total_g);
  const float* cs = colsum + (size_t)b * DIM;
  float* orow = out + (size_t)grow * DIM;
  #pragma unroll
  for (int j = 0; j < 4; ++j) {
    f32x4 c = *(const f32x4*)(cs + j * 256 + lane * 4);
    f32x4 o;
    #pragma unroll
    for (int e = 0; e < 4; ++e) o[e] = (c[e] + oacc[j][e]) * inv;
    *(f32x4*)(orow + j * 256 + lane * 4) = o;
  }
}

extern "C" void kernel_launch(void* const* d_in, const int* in_sizes, int n_in,
                              void* d_out, int out_size, void* d_ws, size_t ws_size,
                              hipStream_t stream) {
  const float* queries = (const float*)d_in[0];
  const float* keys    = (const float*)d_in[1];
  const float* values  = (const float*)d_in[2];
  const int*   mask    = (const int*)d_in[3];
  const float* W       = (const float*)d_in[4];
  float* out = (float*)d_out;

  // ws layout (bytes), total 192 MB (within proven footprint):
  //   [0, 112M)    cand float2[16384][32][28]
  //       q16 aliases [0, 32M)   (dead before gemm_scores)
  //       w16 aliases [32M, 34M) (dead before gemm_scores)
  //   [112M, 114M) counts int[16384][32]
  //   [114M, 118M) maskbits u64[16384][32]
  //   [118M, +32K) colsum f32 8192
  //   [119M, 120M) partial f32 [32][8192]
  //   [128M, 160M) qp16 f16 [16384][1024]
  //   [160M, 192M) k16  f16 [8][2048][1024]
  char* base = (char*)d_ws;
  float2* cand   = (float2*)base;
  f16*   q16     = (f16*)base;
  f16*   w16     = (f16*)(base + (size_t)32 * 1024 * 1024);
  int*   counts  = (int*)(base + (size_t)112 * 1024 * 1024);
  unsigned long long* maskbits =
      (unsigned long long*)(base + (size_t)114 * 1024 * 1024);
  float* colsum  = (float*)(base + (size_t)118 * 1024 * 1024);
  float* partial = (float*)(base + (size_t)119 * 1024 * 1024);
  f16*   qp16    = (f16*)(base + (size_t)128 * 1024 * 1024);
  f16*   k16     = (f16*)(base + (size_t)160 * 1024 * 1024);

  prep_kernel<<<36864, 256, 0, stream>>>(queries, keys, W, (const int4*)mask,
                                         values, q16, k16, w16, maskbits,
                                         partial);
  gemm_qproj<<<1056, 256, 0, stream>>>(q16, w16, qp16, partial, colsum);
  gemm_scores<<<2048, 256, 0, stream>>>(qp16, k16, maskbits, cand, counts);
  topk_kernel<<<2048, 512, 0, stream>>>(cand, counts, values, colsum, out);
}

// Round 13
// 296.721 us; speedup vs baseline: 1.1796x; 1.0126x over previous
//
#include <hip/hip_runtime.h>
#include <math.h>

#define BATCH 8
#define SEQ   2048      // LQ == LK
#define DIM   1024      // DQ == DK == DV
#define TOPK  64
#define NEGMASK -1e30f
#define CAND_THRESH 16.0f   // drop alpha <= e^-16: g <= 1.1e-7, invisible at 2e-3
#define CAP 28              // candidate slots per [row][tile][half]

typedef _Float16 f16;
typedef _Float16 f16x8 __attribute__((ext_vector_type(8)));
typedef float f32x4 __attribute__((ext_vector_type(4)));

// async global->LDS, 16B per lane; LDS dest is wave-uniform base + lane*16.
__device__ __forceinline__ void async_load16(const void* g, void* l) {
  __builtin_amdgcn_global_load_lds(
      (const __attribute__((address_space(1))) void*)g,
      (__attribute__((address_space(3))) void*)l, 16, 0, 0);
}

__device__ __forceinline__ uint2 cvt4(float4 v) {
  union { f16 h[4]; uint2 u; } pk;
  pk.h[0] = (f16)v.x; pk.h[1] = (f16)v.y; pk.h[2] = (f16)v.z; pk.h[3] = (f16)v.w;
  return pk.u;
}

// ---------------- prep: cvt(Q), cvt(keys), cvt(W), pack_mask, colsum_partial ----------------
// ILP restructure (G11/G13): 4 independent 16B loads per thread in cvt
// branches; 4 independent mask groups per wave per iter. Block-range dispatch.
// mask-bit layout: word (grp*4 + j), bit l <-> column grp*256 + 4*l + j.
__global__ __launch_bounds__(256) void prep_kernel(
    const float* __restrict__ queries, const float* __restrict__ keys,
    const float* __restrict__ W,
    const int4* __restrict__ mask4, const float* __restrict__ values,
    f16* __restrict__ q16, f16* __restrict__ k16, f16* __restrict__ w16,
    unsigned long long* __restrict__ mb, float* __restrict__ partial) {
  const int blk = blockIdx.x;
  if (blk < 8192) {                        // cvt Q / K: 4M float4 each, 4/thread
    const float4* src = (const float4*)(blk < 4096 ? queries : keys);
    uint2* dst = (uint2*)(blk < 4096 ? q16 : k16);
    const int base = (blk & 4095) * 1024 + threadIdx.x;
    float4 v0 = src[base];
    float4 v1 = src[base + 256];
    float4 v2 = src[base + 512];
    float4 v3 = src[base + 768];
    dst[base]       = cvt4(v0);
    dst[base + 256] = cvt4(v1);
    dst[base + 512] = cvt4(v2);
    dst[base + 768] = cvt4(v3);
  } else if (blk < 8448) {                 // cvt W: 256K float4, 4/thread
    const float4* src = (const float4*)W;
    uint2* dst = (uint2*)w16;
    const int base = (blk - 8192) * 1024 + threadIdx.x;
    float4 v0 = src[base];
    float4 v1 = src[base + 256];
    float4 v2 = src[base + 512];
    float4 v3 = src[base + 768];
    dst[base]       = cvt4(v0);
    dst[base + 256] = cvt4(v1);
    dst[base + 512] = cvt4(v2);
    dst[base + 768] = cvt4(v3);
  } else if (blk < 10496) {                // pack_mask (2048 virtual blocks, 4-deep)
    const int bid = blk - 8448;
    const int wave = threadIdx.x >> 6, lane = threadIdx.x & 63;
    const size_t nGrp = (size_t)16384 * 8;
    for (size_t g = (size_t)bid * 16 + wave * 4; g < nGrp; g += 2048 * 16) {
      int4 v0 = mask4[(g + 0) * 64 + lane];
      int4 v1 = mask4[(g + 1) * 64 + lane];
      int4 v2 = mask4[(g + 2) * 64 + lane];
      int4 v3 = mask4[(g + 3) * 64 + lane];
      unsigned long long a0 = __ballot(v0.x != 0);
      unsigned long long a1 = __ballot(v0.y != 0);
      unsigned long long a2 = __ballot(v0.z != 0);
      unsigned long long a3 = __ballot(v0.w != 0);
      unsigned long long b0 = __ballot(v1.x != 0);
      unsigned long long b1 = __ballot(v1.y != 0);
      unsigned long long b2 = __ballot(v1.z != 0);
      unsigned long long b3 = __ballot(v1.w != 0);
      unsigned long long c0 = __ballot(v2.x != 0);
      unsigned long long c1 = __ballot(v2.y != 0);
      unsigned long long c2 = __ballot(v2.z != 0);
      unsigned long long c3 = __ballot(v2.w != 0);
      unsigned long long d0 = __ballot(v3.x != 0);
      unsigned long long d1 = __ballot(v3.y != 0);
      unsigned long long d2 = __ballot(v3.z != 0);
      unsigned long long d3 = __ballot(v3.w != 0);
      if (lane == 0) {
        mb[g * 4 + 0]  = a0; mb[g * 4 + 1]  = a1;
        mb[g * 4 + 2]  = a2; mb[g * 4 + 3]  = a3;
        mb[g * 4 + 4]  = b0; mb[g * 4 + 5]  = b1;
        mb[g * 4 + 6]  = b2; mb[g * 4 + 7]  = b3;
        mb[g * 4 + 8]  = c0; mb[g * 4 + 9]  = c1;
        mb[g * 4 + 10] = c2; mb[g * 4 + 11] = c3;
        mb[g * 4 + 12] = d0; mb[g * 4 + 13] = d1;
        mb[g * 4 + 14] = d2; mb[g * 4 + 15] = d3;
      }
    }
  } else {                                 // colsum_partial (1024 virtual blocks)
    const int bid = blk - 10496;           // tc(32) x b(8) x dg(4)
    int tc = bid >> 5;
    int b  = (bid >> 2) & 7;
    int dg = bid & 3;
    int d  = dg * 256 + threadIdx.x;
    const float* vp = values + ((size_t)b * SEQ + (size_t)tc * 64) * DIM + d;
    float s = 0.f;
    #pragma unroll 8
    for (int t = 0; t < 64; ++t) s += vp[(size_t)t * DIM];
    partial[((size_t)tc * BATCH + b) * DIM + d] = s;
  }
}

// ---------------- MFMA bt-GEMM core (fp16, counted-vmcnt 2-phase, 128²) ----------------
// r10 core, byte-identical (measured: 110-112 µs scores, MfmaUtil 26.7%, 0 conflicts).
//   STAGE(nxt) ; vmcnt(4) [prev step's loads landed]
//   s_barrier ; ds_read(cur)+MFMA ; s_barrier.  Tail: vmcnt(0).
// Slot XOR-swizzle (rule #21): linear LDS dest, inverse-swizzled global src,
// swizzled ds_read_b128.

#define STAGEK(KOFF, BUF)                                                   \
  async_load16(srcA0 + (KOFF), smA + (BUF) * 8192 + wave * 2048);           \
  async_load16(srcA1 + (KOFF), smA + (BUF) * 8192 + wave * 2048 + 1024);    \
  async_load16(srcB0 + (KOFF), smB + (BUF) * 8192 + wave * 2048);           \
  async_load16(srcB1 + (KOFF), smB + (BUF) * 8192 + wave * 2048 + 1024);

#define GEMM_PROLOGUE(APTR, BPTR)                                           \
  const int tid = threadIdx.x;                                              \
  const int wave = tid >> 6, lane = tid & 63;                               \
  const int wm = (wave >> 1) * 64, wn = (wave & 1) * 64;                    \
  const int r0 = wave * 32 + (lane >> 2);                                   \
  const int c16 = (lane & 3) ^ ((r0 >> 1) & 3);                            \
  const f16* srcA0 = (APTR) + (size_t)(m0 + r0) * DIM + c16 * 8;           \
  const f16* srcA1 = (APTR) + (size_t)(m0 + r0 + 16) * DIM + c16 * 8;      \
  const f16* srcB0 = (BPTR) + (size_t)(n0 + r0) * DIM + c16 * 8;           \
  const f16* srcB1 = (BPTR) + (size_t)(n0 + r0 + 16) * DIM + c16 * 8;      \
  int offA[4], offB[4];                                                     \
  _Pragma("unroll")                                                         \
  for (int i = 0; i < 4; ++i) {                                             \
    int r = wm + i * 16 + (lane & 15);                                      \
    offA[i] = r * 64 + ((lane >> 4) ^ ((r >> 1) & 3)) * 16;                 \
    int rn = wn + i * 16 + (lane & 15);                                     \
    offB[i] = rn * 64 + ((lane >> 4) ^ ((rn >> 1) & 3)) * 16;               \
  }                                                                         \
  f32x4 acc[4][4];                                                          \
  _Pragma("unroll")                                                         \
  for (int i = 0; i < 4; ++i)                                               \
    _Pragma("unroll")                                                       \
    for (int j = 0; j < 4; ++j)                                             \
      acc[i][j] = (f32x4){0.f, 0.f, 0.f, 0.f};                              \
  STAGEK(0, 0)                                                              \
  int cur = 0;                                                              \
  for (int k0 = 0; k0 < DIM; k0 += 32) {                                    \
    const int nxt = cur ^ 1;                                                \
    if (k0 + 32 < DIM) {                                                    \
      STAGEK(k0 + 32, nxt)                                                  \
      asm volatile("s_waitcnt vmcnt(4)" ::: "memory");                      \
    } else {                                                                \
      asm volatile("s_waitcnt vmcnt(0)" ::: "memory");                      \
    }                                                                       \
    __builtin_amdgcn_s_barrier();                                           \
    asm volatile("" ::: "memory");                                          \
    f16x8 af[4], bf[4];                                                     \
    _Pragma("unroll")                                                       \
    for (int i = 0; i < 4; ++i) {                                           \
      af[i] = *(const f16x8*)(smA + cur * 8192 + offA[i]);                  \
      bf[i] = *(const f16x8*)(smB + cur * 8192 + offB[i]);                  \
    }                                                                       \
    _Pragma("unroll")                                                       \
    for (int i = 0; i < 4; ++i)                                             \
      _Pragma("unroll")                                                     \
      for (int j = 0; j < 4; ++j)                                           \
        acc[i][j] = __builtin_amdgcn_mfma_f32_16x16x32_f16(                 \
            af[i], bf[j], acc[i][j], 0, 0, 0);                              \
    asm volatile("" ::: "memory");                                          \
    __builtin_amdgcn_s_barrier();                                           \
    cur = nxt;                                                              \
  }

// gemm_qproj + fused colsum_reduce (blocks >= 1024)
__global__ __launch_bounds__(256, 3) void gemm_qproj(
    const f16* __restrict__ A, const f16* __restrict__ Bw,
    f16* __restrict__ C,
    const float* __restrict__ partial, float* __restrict__ colsum) {
  __shared__ __align__(128) char smA[16384];
  __shared__ __align__(128) char smB[16384];
  if (blockIdx.x >= 1024) {                // colsum_reduce (32 virtual blocks)
    int idx = ((int)blockIdx.x - 1024) * 256 + threadIdx.x;   // 8192
    float s = 0.f;
    #pragma unroll
    for (int tc = 0; tc < 32; ++tc) s += partial[(size_t)tc * 8192 + idx];
    colsum[idx] = s;
    return;
  }
  // XCD-swizzled 1D grid: 1024 blocks, 8 n-tiles x 128 m-tiles
  const int swz = ((int)blockIdx.x & 7) * 128 + ((int)blockIdx.x >> 3);
  const int m0 = (swz >> 3) * 128;
  const int n0 = (swz & 7) * 128;
  GEMM_PROLOGUE(A, Bw)
  // C/D layout (verified r2+): col = lane&15, row = (lane>>4)*4 + reg
  const int cr = m0 + wm + (lane >> 4) * 4;
  const int cc = n0 + wn + (lane & 15);
  #pragma unroll
  for (int i = 0; i < 4; ++i)
    #pragma unroll
    for (int j = 0; j < 4; ++j)
      #pragma unroll
      for (int reg = 0; reg < 4; ++reg)
        C[(size_t)(cr + i * 16 + reg) * DIM + cc + j * 16] = (f16)acc[i][j][reg];
}

// scores GEMM + fused mask + per-row tile-max + candidate emission (r10 verbatim).
// Emits, per [row][128-col tile][64-col half], candidates
// {s > tilemax(row,128 cols) - 16} (superset of global {s > mv-16}).
__global__ __launch_bounds__(256, 3) void gemm_scores(
    const f16* __restrict__ QP, const f16* __restrict__ K16,
    const unsigned long long* __restrict__ maskbits,  // [16384][8grp][4jw]
    float2* __restrict__ cand,                        // [16384][32][CAP]
    int* __restrict__ counts) {                       // [16384][32]
  __shared__ __align__(128) char smA[16384];
  __shared__ __align__(128) char smB[16384];
  // XCD-swizzled 1D grid: 2048 blocks; XCD x gets m-band = batch x.
  const int swz = ((int)blockIdx.x & 7) * 256 + ((int)blockIdx.x >> 3);
  const int m0 = (swz >> 4) * 128;     // global flat q-row tile
  const int n0 = (swz & 15) * 128;     // t col within batch
  const int b  = m0 >> 11;
  const f16* Bk = K16 + (size_t)b * SEQ * DIM;
  GEMM_PROLOGUE(QP, Bk)

  const int g  = lane >> 4;    // 16-lane group = 4-row band
  const int lc = lane & 15;    // col within 16

  // apply mask bits: word = grp*4 + (lc&3), bit = basebit + j*4 + (lc>>2)
  const int grp = (n0 + wn) >> 8;
  const int basebit = ((n0 + wn) & 255) >> 2;
  #pragma unroll
  for (int i = 0; i < 4; ++i)
    #pragma unroll
    for (int reg = 0; reg < 4; ++reg) {
      const int r = wm + i * 16 + g * 4 + reg;
      const unsigned long long mw =
          maskbits[(size_t)(m0 + r) * 32 + grp * 4 + (lc & 3)];
      #pragma unroll
      for (int j = 0; j < 4; ++j)
        if (!((mw >> (basebit + j * 4 + (lc >> 2))) & 1ull))
          acc[i][j][reg] = NEGMASK;
    }

  // per-row max over this wave's 64 cols -> LDS halfmax[128][2]
  float* hm = (float*)smA;   // LDS free after final K-loop barrier
  #pragma unroll
  for (int i = 0; i < 4; ++i)
    #pragma unroll
    for (int reg = 0; reg < 4; ++reg) {
      const int r = wm + i * 16 + g * 4 + reg;
      float m4 = fmaxf(fmaxf(acc[i][0][reg], acc[i][1][reg]),
                       fmaxf(acc[i][2][reg], acc[i][3][reg]));
      #pragma unroll
      for (int off = 8; off >= 1; off >>= 1) m4 = fmaxf(m4, __shfl_xor(m4, off));
      if (lc == 0) hm[r * 2 + (wn >> 6)] = m4;
    }
  __syncthreads();

  // ballot-compact candidates (deterministic: slot = running popcount)
  const int pairbase = (n0 >> 7) * 2 + (wn >> 6);   // tile*2 + half
  #pragma unroll
  for (int i = 0; i < 4; ++i)
    #pragma unroll
    for (int reg = 0; reg < 4; ++reg) {
      const int r = wm + i * 16 + g * 4 + reg;
      const float tm = fmaxf(hm[r * 2], hm[r * 2 + 1]);
      const float thresh = fmaxf(tm - CAND_THRESH, -1e29f);
      float2* slot = cand + ((size_t)(m0 + r) * 32 + pairbase) * CAP;
      int cnt = 0;
      #pragma unroll
      for (int j = 0; j < 4; ++j) {
        const float s = acc[i][j][reg];
        const bool c = s > thresh;
        const unsigned long long bal = __ballot(c);
        const int seg = (int)((bal >> (g * 16)) & 0xFFFFull);
        const int pos = cnt + __popc(seg & ((1 << lc) - 1));
        if (c && pos < CAP) {
          float2 e; e.x = s; e.y = __int_as_float(n0 + wn + j * 16 + lc);
          slot[pos] = e;
        }
        cnt += __popc(seg);
      }
      if (lc == 0) counts[(size_t)(m0 + r) * 32 + pairbase] = cnt < CAP ? cnt : CAP;
    }
}

// ---------------- topk from candidate lists (r10 verbatim) ----------------
__global__ __launch_bounds__(512) void topk_kernel(
    const float2* __restrict__ cand,       // [16384][32][CAP]
    const int*    __restrict__ counts,     // [16384][32]
    const float*  __restrict__ values,     // [8][2048][1024]
    const float*  __restrict__ colsum,     // [8][1024]
    float* __restrict__ out)               // [16384][1024]
{
  __shared__ float ssc[8][128];
  __shared__ int   sidx[8][128];
  const int wave = threadIdx.x >> 6;
  const int lane = threadIdx.x & 63;
  const int grow = blockIdx.x * 8 + wave;      // global flat q-row
  const int b    = grow >> 11;
  float* msc = ssc[wave];
  int*   mix = sidx[wave];

  int cnt_p = 0;
  if (lane < 32) cnt_p = counts[(size_t)grow * 32 + lane];
  const float2* myslots = cand + ((size_t)grow * 32 + lane) * CAP;

  // pass 1: global row max over candidates
  float mv = -3e38f;
  for (int k = 0; k < cnt_p; ++k) mv = fmaxf(mv, myslots[k].x);
  #pragma unroll
  for (int off = 32; off > 0; off >>= 1) mv = fmaxf(mv, __shfl_xor(mv, off));
  const bool dead = (mv <= -1e29f);   // fully-masked row -> uniform softmax

  float total_g = 0.f;
  f32x4 oacc[4];
  #pragma unroll
  for (int j = 0; j < 4; ++j) oacc[j] = (f32x4){0.f, 0.f, 0.f, 0.f};
  const float* vbase = values + (size_t)b * SEQ * DIM;

  if (!dead) {
    const float thresh = mv - CAND_THRESH;
    // pass 2: filter count + Z partial
    int f = 0; float zp = 0.f;
    for (int k = 0; k < cnt_p; ++k) {
      float s = myslots[k].x;
      if (s > thresh) { ++f; zp += __expf(s - mv); }
    }
    // prefix over 64 lanes for deterministic compaction order
    int incl = f;
    #pragma unroll
    for (int off = 1; off < 64; off <<= 1) {
      int t = __shfl_up(incl, off);
      if (lane >= off) incl += t;
    }
    const int base = incl - f;
    const int F = __shfl(incl, 63);
    #pragma unroll
    for (int off = 32; off > 0; off >>= 1) zp += __shfl_xor(zp, off);
    const float Z = zp;
    // compact filtered candidates to LDS (order: (pair, slot))
    int w = 0;
    for (int k = 0; k < cnt_p; ++k) {
      float2 cv = myslots[k];
      if (cv.x > thresh) {
        int p = base + w;
        if (p < 128) { msc[p] = cv.x; mix[p] = __float_as_int(cv.y); }
        ++w;
      }
    }
    asm volatile("s_waitcnt lgkmcnt(0)" ::: "memory");

    if (F <= TOPK) {
      // common path: filtered set == significant top-k members
      for (int c = 0; c < F; ++c) {
        float g = expm1f(__expf(msc[c] - mv) / Z);
        total_g += g;
        const float* vrow = vbase + (size_t)mix[c] * DIM;
        #pragma unroll
        for (int j = 0; j < 4; ++j) {
          f32x4 v = *(const f32x4*)(vrow + j * 256 + lane * 4);
          #pragma unroll
          for (int e = 0; e < 4; ++e) oacc[j][e] = fmaf(g, v[e], oacc[j][e]);
        }
      }
    } else {
      // rare path: exact top-64 by (score desc, idx asc) from the list
      const int nlist = F < 128 ? F : 128;
      for (int itk = 0; itk < TOPK; ++itk) {
        float bv = -3e38f; int bi = 1 << 30; int bsl = -1;
        #pragma unroll
        for (int h = 0; h < 2; ++h) {
          int sl = lane + h * 64;
          if (sl < nlist) {
            float v = msc[sl]; int id = mix[sl];
            if (v > bv || (v == bv && id < bi)) { bv = v; bi = id; bsl = sl; }
          }
        }
        #pragma unroll
        for (int off = 32; off > 0; off >>= 1) {
          float ov = __shfl_xor(bv, off);
          int   oi = __shfl_xor(bi, off);
          int   os = __shfl_xor(bsl, off);
          if (ov > bv || (ov == bv && oi < bi)) { bv = ov; bi = oi; bsl = os; }
        }
        if (bv <= -1e29f) break;
        float g = expm1f(__expf(bv - mv) / Z);
        total_g += g;
        const float* vrow = vbase + (size_t)bi * DIM;
        #pragma unroll
        for (int j = 0; j < 4; ++j) {
          f32x4 v = *(const f32x4*)(vrow + j * 256 + lane * 4);
          #pragma unroll
          for (int e = 0; e < 4; ++e) oacc[j][e] = fmaf(g, v[e], oacc[j][e]);
        }
        if (lane == 0) msc[bsl] = -3e38f;
        asm volatile("s_waitcnt lgkmcnt(0)" ::: "memory");
      }
    }
  }

  // out = (colsum + sum g*v) / (2048 + sum g)
  const float inv = 1.0f / (2048.0f + total_g);
  const float* cs = colsum + (size_t)b * DIM;
  float* orow = out + (size_t)grow * DIM;
  #pragma unroll
  for (int j = 0; j < 4; ++j) {
    f32x4 c = *(const f32x4*)(cs + j * 256 + lane * 4);
    f32x4 o;
    #pragma unroll
    for (int e = 0; e < 4; ++e) o[e] = (c[e] + oacc[j][e]) * inv;
    *(f32x4*)(orow + j * 256 + lane * 4) = o;
  }
}

extern "C" void kernel_launch(void* const* d_in, const int* in_sizes, int n_in,
                              void* d_out, int out_size, void* d_ws, size_t ws_size,
                              hipStream_t stream) {
  const float* queries = (const float*)d_in[0];
  const float* keys    = (const float*)d_in[1];
  const float* values  = (const float*)d_in[2];
  const int*   mask    = (const int*)d_in[3];
  const float* W       = (const float*)d_in[4];
  float* out = (float*)d_out;

  // ws layout (bytes), total 192 MB (within proven footprint):
  //   [0, 112M)    cand float2[16384][32][28]
  //       q16 aliases [0, 32M)   (dead before gemm_scores)
  //       w16 aliases [32M, 34M) (dead before gemm_scores)
  //   [112M, 114M) counts int[16384][32]
  //   [114M, 118M) maskbits u64[16384][32]
  //   [118M, +32K) colsum f32 8192
  //   [119M, 120M) partial f32 [32][8192]
  //   [128M, 160M) qp16 f16 [16384][1024]
  //   [160M, 192M) k16  f16 [8][2048][1024]
  char* base = (char*)d_ws;
  float2* cand   = (float2*)base;
  f16*   q16     = (f16*)base;
  f16*   w16     = (f16*)(base + (size_t)32 * 1024 * 1024);
  int*   counts  = (int*)(base + (size_t)112 * 1024 * 1024);
  unsigned long long* maskbits =
      (unsigned long long*)(base + (size_t)114 * 1024 * 1024);
  float* colsum  = (float*)(base + (size_t)118 * 1024 * 1024);
  float* partial = (float*)(base + (size_t)119 * 1024 * 1024);
  f16*   qp16    = (f16*)(base + (size_t)128 * 1024 * 1024);
  f16*   k16     = (f16*)(base + (size_t)160 * 1024 * 1024);

  prep_kernel<<<11520, 256, 0, stream>>>(queries, keys, W, (const int4*)mask,
                                         values, q16, k16, w16, maskbits,
                                         partial);
  gemm_qproj<<<1056, 256, 0, stream>>>(q16, w16, qp16, partial, colsum);
  gemm_scores<<<2048, 256, 0, stream>>>(qp16, k16, maskbits, cand, counts);
  topk_kernel<<<2048, 512, 0, stream>>>(cand, counts, values, colsum, out);
}

// Round 14
// 275.450 us; speedup vs baseline: 1.2707x; 1.0772x over previous
//
#include <hip/hip_runtime.h>
#include <math.h>

#define BATCH 8
#define SEQ   2048      // LQ == LK
#define DIM   1024      // DQ == DK == DV
#define TOPK  64
#define NEGMASK -1e30f
#define CAND_THRESH 16.0f   // drop alpha <= e^-16: g <= 1.1e-7, invisible at 2e-3
#define CAP 28              // candidate slots per [row][tile][half]

typedef _Float16 f16;
typedef _Float16 f16x8 __attribute__((ext_vector_type(8)));
typedef float f32x4 __attribute__((ext_vector_type(4)));

// async global->LDS, 16B per lane; LDS dest is wave-uniform base + lane*16.
__device__ __forceinline__ void async_load16(const void* g, void* l) {
  __builtin_amdgcn_global_load_lds(
      (const __attribute__((address_space(1))) void*)g,
      (__attribute__((address_space(3))) void*)l, 16, 0, 0);
}

__device__ __forceinline__ uint2 cvt4(float4 v) {
  union { f16 h[4]; uint2 u; } pk;
  pk.h[0] = (f16)v.x; pk.h[1] = (f16)v.y; pk.h[2] = (f16)v.z; pk.h[3] = (f16)v.w;
  return pk.u;
}

// ---------------- prep: cvt(Q), cvt(W) only (mask/K/colsum moved) ----------------
__global__ __launch_bounds__(256) void prep_kernel(
    const float* __restrict__ queries, const float* __restrict__ W,
    f16* __restrict__ q16, f16* __restrict__ w16) {
  const int blk = blockIdx.x;
  if (blk < 4096) {                        // cvt Q: 4M float4, 4/thread
    const float4* src = (const float4*)queries;
    uint2* dst = (uint2*)q16;
    const int base = blk * 1024 + threadIdx.x;
    float4 v0 = src[base];
    float4 v1 = src[base + 256];
    float4 v2 = src[base + 512];
    float4 v3 = src[base + 768];
    dst[base]       = cvt4(v0);
    dst[base + 256] = cvt4(v1);
    dst[base + 512] = cvt4(v2);
    dst[base + 768] = cvt4(v3);
  } else {                                 // cvt W: 256K float4, 4/thread
    const float4* src = (const float4*)W;
    uint2* dst = (uint2*)w16;
    const int base = (blk - 4096) * 1024 + threadIdx.x;
    float4 v0 = src[base];
    float4 v1 = src[base + 256];
    float4 v2 = src[base + 512];
    float4 v3 = src[base + 768];
    dst[base]       = cvt4(v0);
    dst[base + 256] = cvt4(v1);
    dst[base + 512] = cvt4(v2);
    dst[base + 768] = cvt4(v3);
  }
}

// ---------------- MFMA bt-GEMM core (fp16, counted-vmcnt 2-phase, 128²) ----------------
// r10 core, byte-identical (measured: ~110 µs scores, MfmaUtil 26.7%, 0 conflicts).
//   STAGE(nxt) ; vmcnt(4) [prev step's loads landed]
//   s_barrier ; ds_read(cur)+MFMA ; s_barrier.  Tail: vmcnt(0).
// Slot XOR-swizzle (rule #21): linear LDS dest, inverse-swizzled global src,
// swizzled ds_read_b128.

#define STAGEK(KOFF, BUF)                                                   \
  async_load16(srcA0 + (KOFF), smA + (BUF) * 8192 + wave * 2048);           \
  async_load16(srcA1 + (KOFF), smA + (BUF) * 8192 + wave * 2048 + 1024);    \
  async_load16(srcB0 + (KOFF), smB + (BUF) * 8192 + wave * 2048);           \
  async_load16(srcB1 + (KOFF), smB + (BUF) * 8192 + wave * 2048 + 1024);

#define GEMM_PROLOGUE(APTR, BPTR)                                           \
  const int tid = threadIdx.x;                                              \
  const int wave = tid >> 6, lane = tid & 63;                               \
  const int wm = (wave >> 1) * 64, wn = (wave & 1) * 64;                    \
  const int r0 = wave * 32 + (lane >> 2);                                   \
  const int c16 = (lane & 3) ^ ((r0 >> 1) & 3);                            \
  const f16* srcA0 = (APTR) + (size_t)(m0 + r0) * DIM + c16 * 8;           \
  const f16* srcA1 = (APTR) + (size_t)(m0 + r0 + 16) * DIM + c16 * 8;      \
  const f16* srcB0 = (BPTR) + (size_t)(n0 + r0) * DIM + c16 * 8;           \
  const f16* srcB1 = (BPTR) + (size_t)(n0 + r0 + 16) * DIM + c16 * 8;      \
  int offA[4], offB[4];                                                     \
  _Pragma("unroll")                                                         \
  for (int i = 0; i < 4; ++i) {                                             \
    int r = wm + i * 16 + (lane & 15);                                      \
    offA[i] = r * 64 + ((lane >> 4) ^ ((r >> 1) & 3)) * 16;                 \
    int rn = wn + i * 16 + (lane & 15);                                     \
    offB[i] = rn * 64 + ((lane >> 4) ^ ((rn >> 1) & 3)) * 16;               \
  }                                                                         \
  f32x4 acc[4][4];                                                          \
  _Pragma("unroll")                                                         \
  for (int i = 0; i < 4; ++i)                                               \
    _Pragma("unroll")                                                       \
    for (int j = 0; j < 4; ++j)                                             \
      acc[i][j] = (f32x4){0.f, 0.f, 0.f, 0.f};                              \
  STAGEK(0, 0)                                                              \
  int cur = 0;                                                              \
  for (int k0 = 0; k0 < DIM; k0 += 32) {                                    \
    const int nxt = cur ^ 1;                                                \
    if (k0 + 32 < DIM) {                                                    \
      STAGEK(k0 + 32, nxt)                                                  \
      asm volatile("s_waitcnt vmcnt(4)" ::: "memory");                      \
    } else {                                                                \
      asm volatile("s_waitcnt vmcnt(0)" ::: "memory");                      \
    }                                                                       \
    __builtin_amdgcn_s_barrier();                                           \
    asm volatile("" ::: "memory");                                          \
    f16x8 af[4], bf[4];                                                     \
    _Pragma("unroll")                                                       \
    for (int i = 0; i < 4; ++i) {                                           \
      af[i] = *(const f16x8*)(smA + cur * 8192 + offA[i]);                  \
      bf[i] = *(const f16x8*)(smB + cur * 8192 + offB[i]);                  \
    }                                                                       \
    _Pragma("unroll")                                                       \
    for (int i = 0; i < 4; ++i)                                             \
      _Pragma("unroll")                                                     \
      for (int j = 0; j < 4; ++j)                                           \
        acc[i][j] = __builtin_amdgcn_mfma_f32_16x16x32_f16(                 \
            af[i], bf[j], acc[i][j], 0, 0, 0);                              \
    asm volatile("" ::: "memory");                                          \
    __builtin_amdgcn_s_barrier();                                           \
    cur = nxt;                                                              \
  }

// gemm_qproj + riders: K-cvt (blocks 1024..5119), colsum_partial (5120..6143).
// Riders' outputs (k16, partial) are consumed only in LATER launches.
__global__ __launch_bounds__(256, 3) void gemm_qproj(
    const f16* __restrict__ A, const f16* __restrict__ Bw,
    f16* __restrict__ C,
    const float* __restrict__ keys, f16* __restrict__ k16,
    const float* __restrict__ values, float* __restrict__ partial) {
  __shared__ __align__(128) char smA[16384];
  __shared__ __align__(128) char smB[16384];
  if (blockIdx.x >= 5120) {                // colsum_partial (1024 virtual blocks)
    const int bid = (int)blockIdx.x - 5120; // tc(32) x b(8) x dg(4)
    int tc = bid >> 5;
    int b  = (bid >> 2) & 7;
    int dg = bid & 3;
    int d  = dg * 256 + threadIdx.x;
    const float* vp = values + ((size_t)b * SEQ + (size_t)tc * 64) * DIM + d;
    float s = 0.f;
    #pragma unroll 8
    for (int t = 0; t < 64; ++t) s += vp[(size_t)t * DIM];
    partial[((size_t)tc * BATCH + b) * DIM + d] = s;
    return;
  }
  if (blockIdx.x >= 1024) {                // K-cvt (4096 virtual blocks, 4/thread)
    const float4* src = (const float4*)keys;
    uint2* dst = (uint2*)k16;
    const int base = ((int)blockIdx.x - 1024) * 1024 + threadIdx.x;
    float4 v0 = src[base];
    float4 v1 = src[base + 256];
    float4 v2 = src[base + 512];
    float4 v3 = src[base + 768];
    dst[base]       = cvt4(v0);
    dst[base + 256] = cvt4(v1);
    dst[base + 512] = cvt4(v2);
    dst[base + 768] = cvt4(v3);
    return;
  }
  // XCD-swizzled: 1024 GEMM blocks, 8 n-tiles x 128 m-tiles
  const int swz = ((int)blockIdx.x & 7) * 128 + ((int)blockIdx.x >> 3);
  const int m0 = (swz >> 3) * 128;
  const int n0 = (swz & 7) * 128;
  GEMM_PROLOGUE(A, Bw)
  // C/D layout (verified r2+): col = lane&15, row = (lane>>4)*4 + reg
  const int cr = m0 + wm + (lane >> 4) * 4;
  const int cc = n0 + wn + (lane & 15);
  #pragma unroll
  for (int i = 0; i < 4; ++i)
    #pragma unroll
    for (int j = 0; j < 4; ++j)
      #pragma unroll
      for (int reg = 0; reg < 4; ++reg)
        C[(size_t)(cr + i * 16 + reg) * DIM + cc + j * 16] = (f16)acc[i][j][reg];
}

// scores GEMM + RAW mask + per-row tile-max + candidate emission.
// Mask read moved here (read-once 128 MB in a BW-headroom kernel; pack_mask
// deleted). Rider: colsum_reduce (blocks >= 2048; partial from prev launch).
__global__ __launch_bounds__(256, 3) void gemm_scores(
    const f16* __restrict__ QP, const f16* __restrict__ K16,
    const int* __restrict__ mask,                     // [16384][2048]
    float2* __restrict__ cand,                        // [16384][32][CAP]
    int* __restrict__ counts,                         // [16384][32]
    const float* __restrict__ partial, float* __restrict__ colsum) {
  __shared__ __align__(128) char smA[16384];
  __shared__ __align__(128) char smB[16384];
  if (blockIdx.x >= 2048) {                // colsum_reduce (32 virtual blocks)
    int idx = ((int)blockIdx.x - 2048) * 256 + threadIdx.x;   // 8192
    float s = 0.f;
    #pragma unroll
    for (int tc = 0; tc < 32; ++tc) s += partial[(size_t)tc * 8192 + idx];
    colsum[idx] = s;
    return;
  }
  // XCD-swizzled: 2048 GEMM blocks; XCD x gets m-band = batch x.
  const int swz = ((int)blockIdx.x & 7) * 256 + ((int)blockIdx.x >> 3);
  const int m0 = (swz >> 4) * 128;     // global flat q-row tile
  const int n0 = (swz & 15) * 128;     // t col within batch
  const int b  = m0 >> 11;
  const f16* Bk = K16 + (size_t)b * SEQ * DIM;
  GEMM_PROLOGUE(QP, Bk)

  const int g  = lane >> 4;    // 16-lane group = 4-row band
  const int lc = lane & 15;    // col within 16

  // apply raw mask: row = m0+r, col = n0+wn + j*16 + lc (coalesced 64B per
  // 16-lane group; each mask int read exactly once chip-wide)
  #pragma unroll
  for (int i = 0; i < 4; ++i)
    #pragma unroll
    for (int reg = 0; reg < 4; ++reg) {
      const int r = wm + i * 16 + g * 4 + reg;
      const int* mp = mask + (size_t)(m0 + r) * SEQ + n0 + wn + lc;
      int m0v = mp[0], m1v = mp[16], m2v = mp[32], m3v = mp[48];
      if (m0v == 0) acc[i][0][reg] = NEGMASK;
      if (m1v == 0) acc[i][1][reg] = NEGMASK;
      if (m2v == 0) acc[i][2][reg] = NEGMASK;
      if (m3v == 0) acc[i][3][reg] = NEGMASK;
    }

  // per-row max over this wave's 64 cols -> LDS halfmax[128][2]
  float* hm = (float*)smA;   // LDS free after final K-loop barrier
  #pragma unroll
  for (int i = 0; i < 4; ++i)
    #pragma unroll
    for (int reg = 0; reg < 4; ++reg) {
      const int r = wm + i * 16 + g * 4 + reg;
      float m4 = fmaxf(fmaxf(acc[i][0][reg], acc[i][1][reg]),
                       fmaxf(acc[i][2][reg], acc[i][3][reg]));
      #pragma unroll
      for (int off = 8; off >= 1; off >>= 1) m4 = fmaxf(m4, __shfl_xor(m4, off));
      if (lc == 0) hm[r * 2 + (wn >> 6)] = m4;
    }
  __syncthreads();

  // ballot-compact candidates (deterministic: slot = running popcount)
  const int pairbase = (n0 >> 7) * 2 + (wn >> 6);   // tile*2 + half
  #pragma unroll
  for (int i = 0; i < 4; ++i)
    #pragma unroll
    for (int reg = 0; reg < 4; ++reg) {
      const int r = wm + i * 16 + g * 4 + reg;
      const float tm = fmaxf(hm[r * 2], hm[r * 2 + 1]);
      const float thresh = fmaxf(tm - CAND_THRESH, -1e29f);
      float2* slot = cand + ((size_t)(m0 + r) * 32 + pairbase) * CAP;
      int cnt = 0;
      #pragma unroll
      for (int j = 0; j < 4; ++j) {
        const float s = acc[i][j][reg];
        const bool c = s > thresh;
        const unsigned long long bal = __ballot(c);
        const int seg = (int)((bal >> (g * 16)) & 0xFFFFull);
        const int pos = cnt + __popc(seg & ((1 << lc) - 1));
        if (c && pos < CAP) {
          float2 e; e.x = s; e.y = __int_as_float(n0 + wn + j * 16 + lc);
          slot[pos] = e;
        }
        cnt += __popc(seg);
      }
      if (lc == 0) counts[(size_t)(m0 + r) * 32 + pairbase] = cnt < CAP ? cnt : CAP;
    }
}

// ---------------- topk from candidate lists (r10 verbatim) ----------------
__global__ __launch_bounds__(512) void topk_kernel(
    const float2* __restrict__ cand,       // [16384][32][CAP]
    const int*    __restrict__ counts,     // [16384][32]
    const float*  __restrict__ values,     // [8][2048][1024]
    const float*  __restrict__ colsum,     // [8][1024]
    float* __restrict__ out)               // [16384][1024]
{
  __shared__ float ssc[8][128];
  __shared__ int   sidx[8][128];
  const int wave = threadIdx.x >> 6;
  const int lane = threadIdx.x & 63;
  const int grow = blockIdx.x * 8 + wave;      // global flat q-row
  const int b    = grow >> 11;
  float* msc = ssc[wave];
  int*   mix = sidx[wave];

  int cnt_p = 0;
  if (lane < 32) cnt_p = counts[(size_t)grow * 32 + lane];
  const float2* myslots = cand + ((size_t)grow * 32 + lane) * CAP;

  // pass 1: global row max over candidates
  float mv = -3e38f;
  for (int k = 0; k < cnt_p; ++k) mv = fmaxf(mv, myslots[k].x);
  #pragma unroll
  for (int off = 32; off > 0; off >>= 1) mv = fmaxf(mv, __shfl_xor(mv, off));
  const bool dead = (mv <= -1e29f);   // fully-masked row -> uniform softmax

  float total_g = 0.f;
  f32x4 oacc[4];
  #pragma unroll
  for (int j = 0; j < 4; ++j) oacc[j] = (f32x4){0.f, 0.f, 0.f, 0.f};
  const float* vbase = values + (size_t)b * SEQ * DIM;

  if (!dead) {
    const float thresh = mv - CAND_THRESH;
    // pass 2: filter count + Z partial
    int f = 0; float zp = 0.f;
    for (int k = 0; k < cnt_p; ++k) {
      float s = myslots[k].x;
      if (s > thresh) { ++f; zp += __expf(s - mv); }
    }
    // prefix over 64 lanes for deterministic compaction order
    int incl = f;
    #pragma unroll
    for (int off = 1; off < 64; off <<= 1) {
      int t = __shfl_up(incl, off);
      if (lane >= off) incl += t;
    }
    const int base = incl - f;
    const int F = __shfl(incl, 63);
    #pragma unroll
    for (int off = 32; off > 0; off >>= 1) zp += __shfl_xor(zp, off);
    const float Z = zp;
    // compact filtered candidates to LDS (order: (pair, slot))
    int w = 0;
    for (int k = 0; k < cnt_p; ++k) {
      float2 cv = myslots[k];
      if (cv.x > thresh) {
        int p = base + w;
        if (p < 128) { msc[p] = cv.x; mix[p] = __float_as_int(cv.y); }
        ++w;
      }
    }
    asm volatile("s_waitcnt lgkmcnt(0)" ::: "memory");

    if (F <= TOPK) {
      // common path: filtered set == significant top-k members
      for (int c = 0; c < F; ++c) {
        float g = expm1f(__expf(msc[c] - mv) / Z);
        total_g += g;
        const float* vrow = vbase + (size_t)mix[c] * DIM;
        #pragma unroll
        for (int j = 0; j < 4; ++j) {
          f32x4 v = *(const f32x4*)(vrow + j * 256 + lane * 4);
          #pragma unroll
          for (int e = 0; e < 4; ++e) oacc[j][e] = fmaf(g, v[e], oacc[j][e]);
        }
      }
    } else {
      // rare path: exact top-64 by (score desc, idx asc) from the list
      const int nlist = F < 128 ? F : 128;
      for (int itk = 0; itk < TOPK; ++itk) {
        float bv = -3e38f; int bi = 1 << 30; int bsl = -1;
        #pragma unroll
        for (int h = 0; h < 2; ++h) {
          int sl = lane + h * 64;
          if (sl < nlist) {
            float v = msc[sl]; int id = mix[sl];
            if (v > bv || (v == bv && id < bi)) { bv = v; bi = id; bsl = sl; }
          }
        }
        #pragma unroll
        for (int off = 32; off > 0; off >>= 1) {
          float ov = __shfl_xor(bv, off);
          int   oi = __shfl_xor(bi, off);
          int   os = __shfl_xor(bsl, off);
          if (ov > bv || (ov == bv && oi < bi)) { bv = ov; bi = oi; bsl = os; }
        }
        if (bv <= -1e29f) break;
        float g = expm1f(__expf(bv - mv) / Z);
        total_g += g;
        const float* vrow = vbase + (size_t)bi * DIM;
        #pragma unroll
        for (int j = 0; j < 4; ++j) {
          f32x4 v = *(const f32x4*)(vrow + j * 256 + lane * 4);
          #pragma unroll
          for (int e = 0; e < 4; ++e) oacc[j][e] = fmaf(g, v[e], oacc[j][e]);
        }
        if (lane == 0) msc[bsl] = -3e38f;
        asm volatile("s_waitcnt lgkmcnt(0)" ::: "memory");
      }
    }
  }

  // out = (colsum + sum g*v) / (2048 + sum g)
  const float inv = 1.0f / (2048.0f + total_g);
  const float* cs = colsum + (size_t)b * DIM;
  float* orow = out + (size_t)grow * DIM;
  #pragma unroll
  for (int j = 0; j < 4; ++j) {
    f32x4 c = *(const f32x4*)(cs + j * 256 + lane * 4);
    f32x4 o;
    #pragma unroll
    for (int e = 0; e < 4; ++e) o[e] = (c[e] + oacc[j][e]) * inv;
    *(f32x4*)(orow + j * 256 + lane * 4) = o;
  }
}

extern "C" void kernel_launch(void* const* d_in, const int* in_sizes, int n_in,
                              void* d_out, int out_size, void* d_ws, size_t ws_size,
                              hipStream_t stream) {
  const float* queries = (const float*)d_in[0];
  const float* keys    = (const float*)d_in[1];
  const float* values  = (const float*)d_in[2];
  const int*   mask    = (const int*)d_in[3];
  const float* W       = (const float*)d_in[4];
  float* out = (float*)d_out;

  // ws layout (bytes), total 192 MB (within proven footprint):
  //   [0, 112M)    cand float2[16384][32][28]
  //       q16 aliases [0, 32M)   (dead before gemm_scores)
  //       w16 aliases [32M, 34M) (dead before gemm_scores)
  //   [112M, 114M) counts int[16384][32]
  //   [118M, +32K) colsum f32 8192
  //   [119M, 120M) partial f32 [32][8192]
  //   [128M, 160M) qp16 f16 [16384][1024]
  //   [160M, 192M) k16  f16 [8][2048][1024]
  char* base = (char*)d_ws;
  float2* cand   = (float2*)base;
  f16*   q16     = (f16*)base;
  f16*   w16     = (f16*)(base + (size_t)32 * 1024 * 1024);
  int*   counts  = (int*)(base + (size_t)112 * 1024 * 1024);
  float* colsum  = (float*)(base + (size_t)118 * 1024 * 1024);
  float* partial = (float*)(base + (size_t)119 * 1024 * 1024);
  f16*   qp16    = (f16*)(base + (size_t)128 * 1024 * 1024);
  f16*   k16     = (f16*)(base + (size_t)160 * 1024 * 1024);

  prep_kernel<<<4352, 256, 0, stream>>>(queries, W, q16, w16);
  gemm_qproj<<<6144, 256, 0, stream>>>(q16, w16, qp16, keys, k16, values, partial);
  gemm_scores<<<2080, 256, 0, stream>>>(qp16, k16, mask, cand, counts,
                                        partial, colsum);
  topk_kernel<<<2048, 512, 0, stream>>>(cand, counts, values, colsum, out);
}

// Round 15
// 274.453 us; speedup vs baseline: 1.2753x; 1.0036x over previous
//
#include <hip/hip_runtime.h>
#include <math.h>

#define BATCH 8
#define SEQ   2048      // LQ == LK
#define DIM   1024      // DQ == DK == DV
#define TOPK  64
#define NEGMASK -1e30f
#define CAND_THRESH 16.0f   // drop alpha <= e^-16: g <= 1.1e-7, invisible at 2e-3
#define CAP 28              // candidate slots per [row][tile][half]

typedef _Float16 f16;
typedef _Float16 f16x8 __attribute__((ext_vector_type(8)));
typedef float f32x4 __attribute__((ext_vector_type(4)));

// async global->LDS, 16B per lane; LDS dest is wave-uniform base + lane*16.
__device__ __forceinline__ void async_load16(const void* g, void* l) {
  __builtin_amdgcn_global_load_lds(
      (const __attribute__((address_space(1))) void*)g,
      (__attribute__((address_space(3))) void*)l, 16, 0, 0);
}

__device__ __forceinline__ uint2 cvt4(float4 v) {
  union { f16 h[4]; uint2 u; } pk;
  pk.h[0] = (f16)v.x; pk.h[1] = (f16)v.y; pk.h[2] = (f16)v.z; pk.h[3] = (f16)v.w;
  return pk.u;
}

// ---------------- prep: cvt(Q), cvt(W) only ----------------
__global__ __launch_bounds__(256) void prep_kernel(
    const float* __restrict__ queries, const float* __restrict__ W,
    f16* __restrict__ q16, f16* __restrict__ w16) {
  const int blk = blockIdx.x;
  if (blk < 4096) {                        // cvt Q: 4M float4, 4/thread
    const float4* src = (const float4*)queries;
    uint2* dst = (uint2*)q16;
    const int base = blk * 1024 + threadIdx.x;
    float4 v0 = src[base];
    float4 v1 = src[base + 256];
    float4 v2 = src[base + 512];
    float4 v3 = src[base + 768];
    dst[base]       = cvt4(v0);
    dst[base + 256] = cvt4(v1);
    dst[base + 512] = cvt4(v2);
    dst[base + 768] = cvt4(v3);
  } else {                                 // cvt W: 256K float4, 4/thread
    const float4* src = (const float4*)W;
    uint2* dst = (uint2*)w16;
    const int base = (blk - 4096) * 1024 + threadIdx.x;
    float4 v0 = src[base];
    float4 v1 = src[base + 256];
    float4 v2 = src[base + 512];
    float4 v3 = src[base + 768];
    dst[base]       = cvt4(v0);
    dst[base + 256] = cvt4(v1);
    dst[base + 512] = cvt4(v2);
    dst[base + 768] = cvt4(v3);
  }
}

// ---------------- MFMA bt-GEMM core (fp16, depth-2 counted-vmcnt, 128²) ----------------
// r14 core upgraded to a 3-buffer distance-2 pipeline: stage K-step k+2 while
// computing k. Steady state vmcnt(8) (= exactly retires step k's 4 loads;
// 8 newer stay in flight); tail decays 8 -> 4 -> 0.
// RAW: buf[k%3] certified by each wave's own vmcnt + barrier1.
// WAR: buf[(k+2)%3] last read at step k-1; those ds_reads completed before
// step k-1's closing barrier, which all waves passed before step k's STAGE.
// LDS 48 KB (3 x [A 8K | B 8K]) -> 3 blocks/CU; VGPR ~68 -> (256,3) holds.
// Slot XOR-swizzle (rule #21) unchanged; SQ_LDS_BANK_CONFLICT==0 verified.

#define STAGEK(KOFF, BUF)                                                   \
  async_load16(srcA0 + (KOFF), smA + (BUF) * 8192 + wave * 2048);           \
  async_load16(srcA1 + (KOFF), smA + (BUF) * 8192 + wave * 2048 + 1024);    \
  async_load16(srcB0 + (KOFF), smB + (BUF) * 8192 + wave * 2048);           \
  async_load16(srcB1 + (KOFF), smB + (BUF) * 8192 + wave * 2048 + 1024);

#define GEMM_PROLOGUE(APTR, BPTR)                                           \
  const int tid = threadIdx.x;                                              \
  const int wave = tid >> 6, lane = tid & 63;                               \
  const int wm = (wave >> 1) * 64, wn = (wave & 1) * 64;                    \
  const int r0 = wave * 32 + (lane >> 2);                                   \
  const int c16 = (lane & 3) ^ ((r0 >> 1) & 3);                            \
  const f16* srcA0 = (APTR) + (size_t)(m0 + r0) * DIM + c16 * 8;           \
  const f16* srcA1 = (APTR) + (size_t)(m0 + r0 + 16) * DIM + c16 * 8;      \
  const f16* srcB0 = (BPTR) + (size_t)(n0 + r0) * DIM + c16 * 8;           \
  const f16* srcB1 = (BPTR) + (size_t)(n0 + r0 + 16) * DIM + c16 * 8;      \
  int offA[4], offB[4];                                                     \
  _Pragma("unroll")                                                         \
  for (int i = 0; i < 4; ++i) {                                             \
    int r = wm + i * 16 + (lane & 15);                                      \
    offA[i] = r * 64 + ((lane >> 4) ^ ((r >> 1) & 3)) * 16;                 \
    int rn = wn + i * 16 + (lane & 15);                                     \
    offB[i] = rn * 64 + ((lane >> 4) ^ ((rn >> 1) & 3)) * 16;               \
  }                                                                         \
  f32x4 acc[4][4];                                                          \
  _Pragma("unroll")                                                         \
  for (int i = 0; i < 4; ++i)                                               \
    _Pragma("unroll")                                                       \
    for (int j = 0; j < 4; ++j)                                             \
      acc[i][j] = (f32x4){0.f, 0.f, 0.f, 0.f};                              \
  STAGEK(0, 0)                                                              \
  STAGEK(32, 1)                                                             \
  int cur = 0;                                                              \
  for (int k0 = 0; k0 < DIM; k0 += 32) {                                    \
    if (k0 + 64 < DIM) {                                                    \
      const int nx2 = cur >= 1 ? cur - 1 : cur + 2;  /* (cur+2)%3 */        \
      STAGEK(k0 + 64, nx2)                                                  \
      asm volatile("s_waitcnt vmcnt(8)" ::: "memory");                      \
    } else if (k0 + 32 < DIM) {                                             \
      asm volatile("s_waitcnt vmcnt(4)" ::: "memory");                      \
    } else {                                                                \
      asm volatile("s_waitcnt vmcnt(0)" ::: "memory");                      \
    }                                                                       \
    __builtin_amdgcn_s_barrier();                                           \
    asm volatile("" ::: "memory");                                          \
    f16x8 af[4], bf[4];                                                     \
    _Pragma("unroll")                                                       \
    for (int i = 0; i < 4; ++i) {                                           \
      af[i] = *(const f16x8*)(smA + cur * 8192 + offA[i]);                  \
      bf[i] = *(const f16x8*)(smB + cur * 8192 + offB[i]);                  \
    }                                                                       \
    _Pragma("unroll")                                                       \
    for (int i = 0; i < 4; ++i)                                             \
      _Pragma("unroll")                                                     \
      for (int j = 0; j < 4; ++j)                                           \
        acc[i][j] = __builtin_amdgcn_mfma_f32_16x16x32_f16(                 \
            af[i], bf[j], acc[i][j], 0, 0, 0);                              \
    asm volatile("" ::: "memory");                                          \
    __builtin_amdgcn_s_barrier();                                           \
    cur = cur == 2 ? 0 : cur + 1;                                           \
  }

// gemm_qproj + riders: K-cvt (blocks 1024..5119), colsum_partial (5120..6143).
// Riders' outputs (k16, partial) are consumed only in LATER launches.
__global__ __launch_bounds__(256, 3) void gemm_qproj(
    const f16* __restrict__ A, const f16* __restrict__ Bw,
    f16* __restrict__ C,
    const float* __restrict__ keys, f16* __restrict__ k16,
    const float* __restrict__ values, float* __restrict__ partial) {
  __shared__ __align__(128) char smA[24576];
  __shared__ __align__(128) char smB[24576];
  if (blockIdx.x >= 5120) {                // colsum_partial (1024 virtual blocks)
    const int bid = (int)blockIdx.x - 5120; // tc(32) x b(8) x dg(4)
    int tc = bid >> 5;
    int b  = (bid >> 2) & 7;
    int dg = bid & 3;
    int d  = dg * 256 + threadIdx.x;
    const float* vp = values + ((size_t)b * SEQ + (size_t)tc * 64) * DIM + d;
    float s = 0.f;
    #pragma unroll 8
    for (int t = 0; t < 64; ++t) s += vp[(size_t)t * DIM];
    partial[((size_t)tc * BATCH + b) * DIM + d] = s;
    return;
  }
  if (blockIdx.x >= 1024) {                // K-cvt (4096 virtual blocks, 4/thread)
    const float4* src = (const float4*)keys;
    uint2* dst = (uint2*)k16;
    const int base = ((int)blockIdx.x - 1024) * 1024 + threadIdx.x;
    float4 v0 = src[base];
    float4 v1 = src[base + 256];
    float4 v2 = src[base + 512];
    float4 v3 = src[base + 768];
    dst[base]       = cvt4(v0);
    dst[base + 256] = cvt4(v1);
    dst[base + 512] = cvt4(v2);
    dst[base + 768] = cvt4(v3);
    return;
  }
  // XCD-swizzled: 1024 GEMM blocks, 8 n-tiles x 128 m-tiles
  const int swz = ((int)blockIdx.x & 7) * 128 + ((int)blockIdx.x >> 3);
  const int m0 = (swz >> 3) * 128;
  const int n0 = (swz & 7) * 128;
  GEMM_PROLOGUE(A, Bw)
  // C/D layout (verified r2+): col = lane&15, row = (lane>>4)*4 + reg
  const int cr = m0 + wm + (lane >> 4) * 4;
  const int cc = n0 + wn + (lane & 15);
  #pragma unroll
  for (int i = 0; i < 4; ++i)
    #pragma unroll
    for (int j = 0; j < 4; ++j)
      #pragma unroll
      for (int reg = 0; reg < 4; ++reg)
        C[(size_t)(cr + i * 16 + reg) * DIM + cc + j * 16] = (f16)acc[i][j][reg];
}

// scores GEMM + RAW mask + per-row tile-max + candidate emission.
// Rider: colsum_reduce (blocks >= 2048; partial from prev launch).
__global__ __launch_bounds__(256, 3) void gemm_scores(
    const f16* __restrict__ QP, const f16* __restrict__ K16,
    const int* __restrict__ mask,                     // [16384][2048]
    float2* __restrict__ cand,                        // [16384][32][CAP]
    int* __restrict__ counts,                         // [16384][32]
    const float* __restrict__ partial, float* __restrict__ colsum) {
  __shared__ __align__(128) char smA[24576];
  __shared__ __align__(128) char smB[24576];
  if (blockIdx.x >= 2048) {                // colsum_reduce (32 virtual blocks)
    int idx = ((int)blockIdx.x - 2048) * 256 + threadIdx.x;   // 8192
    float s = 0.f;
    #pragma unroll
    for (int tc = 0; tc < 32; ++tc) s += partial[(size_t)tc * 8192 + idx];
    colsum[idx] = s;
    return;
  }
  // XCD-swizzled: 2048 GEMM blocks; XCD x gets m-band = batch x.
  const int swz = ((int)blockIdx.x & 7) * 256 + ((int)blockIdx.x >> 3);
  const int m0 = (swz >> 4) * 128;     // global flat q-row tile
  const int n0 = (swz & 15) * 128;     // t col within batch
  const int b  = m0 >> 11;
  const f16* Bk = K16 + (size_t)b * SEQ * DIM;
  GEMM_PROLOGUE(QP, Bk)

  const int g  = lane >> 4;    // 16-lane group = 4-row band
  const int lc = lane & 15;    // col within 16

  // apply raw mask: row = m0+r, col = n0+wn + j*16 + lc (coalesced 64B per
  // 16-lane group; each mask int read exactly once chip-wide)
  #pragma unroll
  for (int i = 0; i < 4; ++i)
    #pragma unroll
    for (int reg = 0; reg < 4; ++reg) {
      const int r = wm + i * 16 + g * 4 + reg;
      const int* mp = mask + (size_t)(m0 + r) * SEQ + n0 + wn + lc;
      int m0v = mp[0], m1v = mp[16], m2v = mp[32], m3v = mp[48];
      if (m0v == 0) acc[i][0][reg] = NEGMASK;
      if (m1v == 0) acc[i][1][reg] = NEGMASK;
      if (m2v == 0) acc[i][2][reg] = NEGMASK;
      if (m3v == 0) acc[i][3][reg] = NEGMASK;
    }

  // per-row max over this wave's 64 cols -> LDS halfmax[128][2]
  float* hm = (float*)smA;   // LDS free after final K-loop barrier
  #pragma unroll
  for (int i = 0; i < 4; ++i)
    #pragma unroll
    for (int reg = 0; reg < 4; ++reg) {
      const int r = wm + i * 16 + g * 4 + reg;
      float m4 = fmaxf(fmaxf(acc[i][0][reg], acc[i][1][reg]),
                       fmaxf(acc[i][2][reg], acc[i][3][reg]));
      #pragma unroll
      for (int off = 8; off >= 1; off >>= 1) m4 = fmaxf(m4, __shfl_xor(m4, off));
      if (lc == 0) hm[r * 2 + (wn >> 6)] = m4;
    }
  __syncthreads();

  // ballot-compact candidates (deterministic: slot = running popcount)
  const int pairbase = (n0 >> 7) * 2 + (wn >> 6);   // tile*2 + half
  #pragma unroll
  for (int i = 0; i < 4; ++i)
    #pragma unroll
    for (int reg = 0; reg < 4; ++reg) {
      const int r = wm + i * 16 + g * 4 + reg;
      const float tm = fmaxf(hm[r * 2], hm[r * 2 + 1]);
      const float thresh = fmaxf(tm - CAND_THRESH, -1e29f);
      float2* slot = cand + ((size_t)(m0 + r) * 32 + pairbase) * CAP;
      int cnt = 0;
      #pragma unroll
      for (int j = 0; j < 4; ++j) {
        const float s = acc[i][j][reg];
        const bool c = s > thresh;
        const unsigned long long bal = __ballot(c);
        const int seg = (int)((bal >> (g * 16)) & 0xFFFFull);
        const int pos = cnt + __popc(seg & ((1 << lc) - 1));
        if (c && pos < CAP) {
          float2 e; e.x = s; e.y = __int_as_float(n0 + wn + j * 16 + lc);
          slot[pos] = e;
        }
        cnt += __popc(seg);
      }
      if (lc == 0) counts[(size_t)(m0 + r) * 32 + pairbase] = cnt < CAP ? cnt : CAP;
    }
}

// ---------------- topk from candidate lists (r10 verbatim) ----------------
__global__ __launch_bounds__(512) void topk_kernel(
    const float2* __restrict__ cand,       // [16384][32][CAP]
    const int*    __restrict__ counts,     // [16384][32]
    const float*  __restrict__ values,     // [8][2048][1024]
    const float*  __restrict__ colsum,     // [8][1024]
    float* __restrict__ out)               // [16384][1024]
{
  __shared__ float ssc[8][128];
  __shared__ int   sidx[8][128];
  const int wave = threadIdx.x >> 6;
  const int lane = threadIdx.x & 63;
  const int grow = blockIdx.x * 8 + wave;      // global flat q-row
  const int b    = grow >> 11;
  float* msc = ssc[wave];
  int*   mix = sidx[wave];

  int cnt_p = 0;
  if (lane < 32) cnt_p = counts[(size_t)grow * 32 + lane];
  const float2* myslots = cand + ((size_t)grow * 32 + lane) * CAP;

  // pass 1: global row max over candidates
  float mv = -3e38f;
  for (int k = 0; k < cnt_p; ++k) mv = fmaxf(mv, myslots[k].x);
  #pragma unroll
  for (int off = 32; off > 0; off >>= 1) mv = fmaxf(mv, __shfl_xor(mv, off));
  const bool dead = (mv <= -1e29f);   // fully-masked row -> uniform softmax

  float total_g = 0.f;
  f32x4 oacc[4];
  #pragma unroll
  for (int j = 0; j < 4; ++j) oacc[j] = (f32x4){0.f, 0.f, 0.f, 0.f};
  const float* vbase = values + (size_t)b * SEQ * DIM;

  if (!dead) {
    const float thresh = mv - CAND_THRESH;
    // pass 2: filter count + Z partial
    int f = 0; float zp = 0.f;
    for (int k = 0; k < cnt_p; ++k) {
      float s = myslots[k].x;
      if (s > thresh) { ++f; zp += __expf(s - mv); }
    }
    // prefix over 64 lanes for deterministic compaction order
    int incl = f;
    #pragma unroll
    for (int off = 1; off < 64; off <<= 1) {
      int t = __shfl_up(incl, off);
      if (lane >= off) incl += t;
    }
    const int base = incl - f;
    const int F = __shfl(incl, 63);
    #pragma unroll
    for (int off = 32; off > 0; off >>= 1) zp += __shfl_xor(zp, off);
    const float Z = zp;
    // compact filtered candidates to LDS (order: (pair, slot))
    int w = 0;
    for (int k = 0; k < cnt_p; ++k) {
      float2 cv = myslots[k];
      if (cv.x > thresh) {
        int p = base + w;
        if (p < 128) { msc[p] = cv.x; mix[p] = __float_as_int(cv.y); }
        ++w;
      }
    }
    asm volatile("s_waitcnt lgkmcnt(0)" ::: "memory");

    if (F <= TOPK) {
      // common path: filtered set == significant top-k members
      for (int c = 0; c < F; ++c) {
        float g = expm1f(__expf(msc[c] - mv) / Z);
        total_g += g;
        const float* vrow = vbase + (size_t)mix[c] * DIM;
        #pragma unroll
        for (int j = 0; j < 4; ++j) {
          f32x4 v = *(const f32x4*)(vrow + j * 256 + lane * 4);
          #pragma unroll
          for (int e = 0; e < 4; ++e) oacc[j][e] = fmaf(g, v[e], oacc[j][e]);
        }
      }
    } else {
      // rare path: exact top-64 by (score desc, idx asc) from the list
      const int nlist = F < 128 ? F : 128;
      for (int itk = 0; itk < TOPK; ++itk) {
        float bv = -3e38f; int bi = 1 << 30; int bsl = -1;
        #pragma unroll
        for (int h = 0; h < 2; ++h) {
          int sl = lane + h * 64;
          if (sl < nlist) {
            float v = msc[sl]; int id = mix[sl];
            if (v > bv || (v == bv && id < bi)) { bv = v; bi = id; bsl = sl; }
          }
        }
        #pragma unroll
        for (int off = 32; off > 0; off >>= 1) {
          float ov = __shfl_xor(bv, off);
          int   oi = __shfl_xor(bi, off);
          int   os = __shfl_xor(bsl, off);
          if (ov > bv || (ov == bv && oi < bi)) { bv = ov; bi = oi; bsl = os; }
        }
        if (bv <= -1e29f) break;
        float g = expm1f(__expf(bv - mv) / Z);
        total_g += g;
        const float* vrow = vbase + (size_t)bi * DIM;
        #pragma unroll
        for (int j = 0; j < 4; ++j) {
          f32x4 v = *(const f32x4*)(vrow + j * 256 + lane * 4);
          #pragma unroll
          for (int e = 0; e < 4; ++e) oacc[j][e] = fmaf(g, v[e], oacc[j][e]);
        }
        if (lane == 0) msc[bsl] = -3e38f;
        asm volatile("s_waitcnt lgkmcnt(0)" ::: "memory");
      }
    }
  }

  // out = (colsum + sum g*v) / (2048 + sum g)
  const float inv = 1.0f / (2048.0f + total_g);
  const float* cs = colsum + (size_t)b * DIM;
  float* orow = out + (size_t)grow * DIM;
  #pragma unroll
  for (int j = 0; j < 4; ++j) {
    f32x4 c = *(const f32x4*)(cs + j * 256 + lane * 4);
    f32x4 o;
    #pragma unroll
    for (int e = 0; e < 4; ++e) o[e] = (c[e] + oacc[j][e]) * inv;
    *(f32x4*)(orow + j * 256 + lane * 4) = o;
  }
}

extern "C" void kernel_launch(void* const* d_in, const int* in_sizes, int n_in,
                              void* d_out, int out_size, void* d_ws, size_t ws_size,
                              hipStream_t stream) {
  const float* queries = (const float*)d_in[0];
  const float* keys    = (const float*)d_in[1];
  const float* values  = (const float*)d_in[2];
  const int*   mask    = (const int*)d_in[3];
  const float* W       = (const float*)d_in[4];
  float* out = (float*)d_out;

  // ws layout (bytes), total 192 MB (within proven footprint):
  //   [0, 112M)    cand float2[16384][32][28]
  //       q16 aliases [0, 32M)   (dead before gemm_scores)
  //       w16 aliases [32M, 34M) (dead before gemm_scores)
  //   [112M, 114M) counts int[16384][32]
  //   [118M, +32K) colsum f32 8192
  //   [119M, 120M) partial f32 [32][8192]
  //   [128M, 160M) qp16 f16 [16384][1024]
  //   [160M, 192M) k16  f16 [8][2048][1024]
  char* base = (char*)d_ws;
  float2* cand   = (float2*)base;
  f16*   q16     = (f16*)base;
  f16*   w16     = (f16*)(base + (size_t)32 * 1024 * 1024);
  int*   counts  = (int*)(base + (size_t)112 * 1024 * 1024);
  float* colsum  = (float*)(base + (size_t)118 * 1024 * 1024);
  float* partial = (float*)(base + (size_t)119 * 1024 * 1024);
  f16*   qp16    = (f16*)(base + (size_t)128 * 1024 * 1024);
  f16*   k16     = (f16*)(base + (size_t)160 * 1024 * 1024);

  prep_kernel<<<4352, 256, 0, stream>>>(queries, W, q16, w16);
  gemm_qproj<<<6144, 256, 0, stream>>>(q16, w16, qp16, keys, k16, values, partial);
  gemm_scores<<<2080, 256, 0, stream>>>(qp16, k16, mask, cand, counts,
                                        partial, colsum);
  topk_kernel<<<2048, 512, 0, stream>>>(cand, counts, values, colsum, out);
}